// Round 3
// baseline (359.136 us; speedup 1.0000x reference)
//
#include <hip/hip_runtime.h>

typedef __bf16 bf16_t;
typedef bf16_t bf16x8 __attribute__((ext_vector_type(8)));
typedef float floatx4 __attribute__((ext_vector_type(4)));

#define L1C 512
#define L2C 512
#define BC  32
#define DC  1024
#define KTOP 256
#define NBIN 4096           // 12-bit bins: sign+exp+3 mantissa bits
#define CAP  1024           // per-block candidate slots
#define FCAP 2048           // final-stage compact capacity

__device__ __forceinline__ unsigned short f2bf(float f) {
    unsigned u = __float_as_uint(f);
    u += 0x7FFFu + ((u >> 16) & 1u);   // RNE (data has no NaNs)
    return (unsigned short)(u >> 16);
}

// async global->LDS, 16B per lane; LDS dest = wave-uniform base + lane*16
__device__ __forceinline__ void g2l16(const unsigned short* g, unsigned short* l) {
    __builtin_amdgcn_global_load_lds((const unsigned int*)g, (unsigned int*)l,
                                     16, 0, 0);
}

__device__ __forceinline__ float decode_key(unsigned k) {
    return __uint_as_float(k & 0x7FFFFFFFu);
}

// ---------------- cast f32 -> bf16 (x4 vectorized) ----------------
__global__ void cast_bf16_kernel(const float* __restrict__ src,
                                 unsigned short* __restrict__ dst, int n4) {
    int i = blockIdx.x * blockDim.x + threadIdx.x;
    if (i < n4) {
        float4 v = reinterpret_cast<const float4*>(src)[i];
        ushort4 o;
        o.x = f2bf(v.x); o.y = f2bf(v.y); o.z = f2bf(v.z); o.w = f2bf(v.w);
        reinterpret_cast<ushort4*>(dst)[i] = o;
    }
}

// ---------------- W[d][e] -> Wt[e][d], bf16 ----------------
__global__ void transpose_cast_kernel(const float* __restrict__ W,
                                      unsigned short* __restrict__ Wt) {
    __shared__ float tile[32][33];
    int d0 = blockIdx.x * 32, e0 = blockIdx.y * 32;
    int tx = threadIdx.x;
    for (int i = threadIdx.y; i < 32; i += 8)
        tile[i][tx] = W[(size_t)(d0 + i) * DC + e0 + tx];
    __syncthreads();
    for (int i = threadIdx.y; i < 32; i += 8)
        Wt[(size_t)(e0 + i) * DC + d0 + tx] = f2bf(tile[tx][i]);
}

// ---------------- zero per-block candidate counters ----------------
__global__ void init_kernel(unsigned* __restrict__ cnt) {
    int gid = blockIdx.x * blockDim.x + threadIdx.x;
    if (gid < BC * 16) cnt[gid] = 0;
}

// ---------------- GEMM1: T[r][e] = sum_d A1[r][d] * Wt[e][d], bf16 out ----
__global__ __launch_bounds__(256) void gemm1_kernel(
    const unsigned short* __restrict__ A,    // [16384,1024] bf16
    const unsigned short* __restrict__ Bt,   // [1024,1024]  bf16 (Wt)
    unsigned short* __restrict__ C) {        // [16384,1024] bf16
    __shared__ unsigned short As[128][32];
    __shared__ unsigned short Bs[128][32];
    int tid = threadIdx.x;
    int wave = tid >> 6, lane = tid & 63;
    int lane15 = lane & 15, quad = lane >> 4;
    int wm = wave >> 1, wn = wave & 1;
    size_t m0 = (size_t)blockIdx.x * 128, n0 = (size_t)blockIdx.y * 128;

    floatx4 zero = {0.f, 0.f, 0.f, 0.f};
    floatx4 acc[4][4];
#pragma unroll
    for (int i = 0; i < 4; i++)
#pragma unroll
        for (int j = 0; j < 4; j++) acc[i][j] = zero;

    for (int k0 = 0; k0 < DC; k0 += 32) {
#pragma unroll
        for (int c = 0; c < 2; c++) {
            int cid = c * 256 + tid;
            int row = cid >> 2, col8 = (cid & 3) * 8;
            unsigned short* lbase = &As[0][0] + (c * 256 + wave * 64) * 8;
            g2l16(&A[(m0 + row) * DC + k0 + col8], lbase);
            unsigned short* lbase2 = &Bs[0][0] + (c * 256 + wave * 64) * 8;
            g2l16(&Bt[(n0 + row) * DC + k0 + col8], lbase2);
        }
        __syncthreads();
        bf16x8 af[4], bfr[4];
#pragma unroll
        for (int mi = 0; mi < 4; mi++)
            af[mi] = *reinterpret_cast<const bf16x8*>(&As[wm * 64 + mi * 16 + lane15][quad * 8]);
#pragma unroll
        for (int ni = 0; ni < 4; ni++)
            bfr[ni] = *reinterpret_cast<const bf16x8*>(&Bs[wn * 64 + ni * 16 + lane15][quad * 8]);
#pragma unroll
        for (int mi = 0; mi < 4; mi++)
#pragma unroll
            for (int ni = 0; ni < 4; ni++)
                acc[mi][ni] = __builtin_amdgcn_mfma_f32_16x16x32_bf16(
                    af[mi], bfr[ni], acc[mi][ni], 0, 0, 0);
        __syncthreads();
    }
#pragma unroll
    for (int mi = 0; mi < 4; mi++)
#pragma unroll
        for (int ni = 0; ni < 4; ni++)
#pragma unroll
            for (int r = 0; r < 4; r++) {
                size_t row = m0 + wm * 64 + mi * 16 + quad * 4 + r;
                size_t col = n0 + wn * 64 + ni * 16 + lane15;
                C[row * DC + col] = f2bf(acc[mi][ni][r]);
            }
}

// ---- GEMM2: S = relu(T_b @ H2_b^T + bias); emit block-local top-k cands ---
__global__ __launch_bounds__(256) void gemm2_kernel(
    const unsigned short* __restrict__ Tm,   // [16384,1024] bf16
    const unsigned short* __restrict__ H2,   // [16384,1024] bf16 (inputs2 layout)
    const int* __restrict__ mask1, const int* __restrict__ mask2,
    const float* __restrict__ bptr,
    unsigned* __restrict__ cand,             // [32*16][CAP]
    unsigned* __restrict__ cnt) {            // [32*16]
    __shared__ unsigned short As[128][32];
    __shared__ unsigned short Bs[128][32];
    __shared__ unsigned lh[NBIN];
    __shared__ unsigned csum[256];
    __shared__ int m1s[128], m2s[128];
    __shared__ unsigned tsh, lcnt;
    int tid = threadIdx.x;
    int wave = tid >> 6, lane = tid & 63;
    int lane15 = lane & 15, quad = lane >> 4;
    int wm = wave >> 1, wn = wave & 1;
    int m0 = blockIdx.x * 128, n0 = blockIdx.y * 128;
    int b = blockIdx.z;
    int gblk = b * 16 + blockIdx.y * 4 + blockIdx.x;
    const size_t ldr = (size_t)BC * DC;      // 32768 row stride
    const unsigned short* Ab = Tm + (size_t)b * DC;
    const unsigned short* Bb = H2 + (size_t)b * DC;

    for (int i = tid; i < NBIN; i += 256) lh[i] = 0;
    if (tid < 128) m1s[tid] = (mask1[(m0 + tid) * BC + b] == 0);
    else           m2s[tid - 128] = (mask2[(n0 + tid - 128) * BC + b] == 0);

    floatx4 zero = {0.f, 0.f, 0.f, 0.f};
    floatx4 acc[4][4];
#pragma unroll
    for (int i = 0; i < 4; i++)
#pragma unroll
        for (int j = 0; j < 4; j++) acc[i][j] = zero;

    for (int k0 = 0; k0 < DC; k0 += 32) {
#pragma unroll
        for (int c = 0; c < 2; c++) {
            int cid = c * 256 + tid;
            int row = cid >> 2, col8 = (cid & 3) * 8;
            unsigned short* lbase = &As[0][0] + (c * 256 + wave * 64) * 8;
            g2l16(&Ab[(size_t)(m0 + row) * ldr + k0 + col8], lbase);
            unsigned short* lbase2 = &Bs[0][0] + (c * 256 + wave * 64) * 8;
            g2l16(&Bb[(size_t)(n0 + row) * ldr + k0 + col8], lbase2);
        }
        __syncthreads();
        bf16x8 af[4], bfr[4];
#pragma unroll
        for (int mi = 0; mi < 4; mi++)
            af[mi] = *reinterpret_cast<const bf16x8*>(&As[wm * 64 + mi * 16 + lane15][quad * 8]);
#pragma unroll
        for (int ni = 0; ni < 4; ni++)
            bfr[ni] = *reinterpret_cast<const bf16x8*>(&Bs[wn * 64 + ni * 16 + lane15][quad * 8]);
#pragma unroll
        for (int mi = 0; mi < 4; mi++)
#pragma unroll
            for (int ni = 0; ni < 4; ni++)
                acc[mi][ni] = __builtin_amdgcn_mfma_f32_16x16x32_bf16(
                    af[mi], bfr[ni], acc[mi][ni], 0, 0, 0);
        __syncthreads();
    }

    float bias = bptr[0];
    // pass 1: local 4096-bin histogram of valid keys (zeros counted privately
    // to avoid same-address LDS atomic storms on the zero bin)
    unsigned zc = 0;
#pragma unroll
    for (int ni = 0; ni < 4; ni++) {
        int jl = wn * 64 + ni * 16 + lane15;
        int v2 = m2s[jl];
#pragma unroll
        for (int mi = 0; mi < 4; mi++)
#pragma unroll
            for (int r = 0; r < 4; r++) {
                int il = wm * 64 + mi * 16 + quad * 4 + r;
                float s = acc[mi][ni][r] + bias;
                if (v2 && m1s[il]) {
                    if (s > 0.f)
                        atomicAdd(&lh[(__float_as_uint(s) | 0x80000000u) >> 20], 1u);
                    else
                        zc++;
                }
            }
    }
    if (zc) atomicAdd(&lh[2048], zc);
    __syncthreads();
    unsigned s16 = 0;
#pragma unroll
    for (int i = 0; i < 16; i++) s16 += lh[tid * 16 + i];
    csum[tid] = s16;
    __syncthreads();
    if (tid == 0) {
        unsigned cum = 0, bin = 2048;
        int found = 0;
        for (int c = 255; c >= 128 && !found; --c) {
            unsigned cs = csum[c];
            if (cum + cs >= KTOP) {
                for (int bb = c * 16 + 15; bb >= c * 16; --bb) {
                    unsigned h = lh[bb];
                    if (cum + h >= KTOP) { bin = (unsigned)bb; found = 1; break; }
                    cum += h;
                }
            } else cum += cs;
        }
        tsh = bin << 20;
        lcnt = 0;
    }
    __syncthreads();
    // pass 2: emit keys >= block-local threshold
    unsigned T = tsh;
    unsigned base = (unsigned)gblk * CAP;
#pragma unroll
    for (int ni = 0; ni < 4; ni++) {
        int jl = wn * 64 + ni * 16 + lane15;
        int v2 = m2s[jl];
#pragma unroll
        for (int mi = 0; mi < 4; mi++)
#pragma unroll
            for (int r = 0; r < 4; r++) {
                int il = wm * 64 + mi * 16 + quad * 4 + r;
                float s = acc[mi][ni][r] + bias;
                s = s > 0.f ? s : 0.f;
                unsigned key = (v2 && m1s[il])
                                   ? (__float_as_uint(s) | 0x80000000u) : 0u;
                if (key >= T) {
                    unsigned p = atomicAdd(&lcnt, 1u);
                    if (p < CAP) cand[base + p] = key;
                }
            }
    }
    __syncthreads();
    if (tid == 0) cnt[gblk] = lcnt < CAP ? lcnt : CAP;
}

// ---- final: per batch, exact top-256 of the <=16*CAP candidates ----
__global__ __launch_bounds__(256) void final_kernel(
    const unsigned* __restrict__ cand, const unsigned* __restrict__ cnt,
    float* __restrict__ out) {
    __shared__ unsigned lh[NBIN];
    __shared__ unsigned sh[FCAP];
    __shared__ unsigned csum[256];
    __shared__ unsigned tsh, scount;
    int b = blockIdx.x, tid = threadIdx.x;
    for (int i = tid; i < NBIN; i += 256) lh[i] = 0;
    for (int i = tid; i < FCAP; i += 256) sh[i] = 0;
    if (tid == 0) scount = 0;
    __syncthreads();
    for (int blk = 0; blk < 16; blk++) {
        unsigned c = cnt[b * 16 + blk];
        const unsigned* p = cand + (size_t)(b * 16 + blk) * CAP;
        for (int i = tid; i < (int)c; i += 256)
            atomicAdd(&lh[p[i] >> 20], 1u);
    }
    __syncthreads();
    unsigned s16 = 0;
#pragma unroll
    for (int i = 0; i < 16; i++) s16 += lh[tid * 16 + i];
    csum[tid] = s16;
    __syncthreads();
    if (tid == 0) {
        unsigned cum = 0, bin = 2048;
        int found = 0;
        for (int c = 255; c >= 128 && !found; --c) {
            unsigned cs = csum[c];
            if (cum + cs >= KTOP) {
                for (int bb = c * 16 + 15; bb >= c * 16; --bb) {
                    unsigned h = lh[bb];
                    if (cum + h >= KTOP) { bin = (unsigned)bb; found = 1; break; }
                    cum += h;
                }
            } else cum += cs;
        }
        tsh = bin << 20;
    }
    __syncthreads();
    unsigned T = tsh;
    for (int blk = 0; blk < 16; blk++) {
        unsigned c = cnt[b * 16 + blk];
        const unsigned* p = cand + (size_t)(b * 16 + blk) * CAP;
        for (int i = tid; i < (int)c; i += 256) {
            unsigned k = p[i];
            if (k >= T) {
                unsigned q = atomicAdd(&scount, 1u);
                if (q < FCAP) sh[q] = k;
            }
        }
    }
    __syncthreads();
    // bitonic sort FCAP descending (zeros pad to the tail)
    for (int k2 = 2; k2 <= FCAP; k2 <<= 1) {
        for (int j2 = k2 >> 1; j2 > 0; j2 >>= 1) {
            for (int idx = tid; idx < FCAP; idx += 256) {
                int ixj = idx ^ j2;
                if (ixj > idx) {
                    unsigned a = sh[idx], c = sh[ixj];
                    bool up = (idx & k2) == 0;
                    if (up ? (a < c) : (a > c)) { sh[idx] = c; sh[ixj] = a; }
                }
            }
            __syncthreads();
        }
    }
    unsigned sc = scount < FCAP ? scount : FCAP;
    int nval = (int)sc < KTOP ? (int)sc : KTOP;
    float fill = nval > 0 ? decode_key(sh[nval - 1]) : -__builtin_inff();
    out[b * KTOP + tid] = (tid < nval) ? decode_key(sh[tid]) : fill;
}

// ---------------- launch ----------------
extern "C" void kernel_launch(void* const* d_in, const int* in_sizes, int n_in,
                              void* d_out, int out_size, void* d_ws, size_t ws_size,
                              hipStream_t stream) {
    const float* in1   = (const float*)d_in[0];   // [512,32,1024]
    const float* in2   = (const float*)d_in[1];   // [512,32,1024]
    const int*   mask1 = (const int*)d_in[2];     // [512,32]
    const int*   mask2 = (const int*)d_in[3];     // [512,32]
    const float* W     = (const float*)d_in[4];   // [1024,1024]
    const float* bias  = (const float*)d_in[5];   // [1]
    float* out = (float*)d_out;

    char* ws = (char*)d_ws;
    size_t off = 0;
    const size_t nElem = (size_t)L1C * BC * DC;       // 16777216
    unsigned short* A1 = (unsigned short*)(ws + off); off += nElem * 2;       // 32 MB
    unsigned short* A2 = (unsigned short*)(ws + off); off += nElem * 2;       // 32 MB
    unsigned short* Wt = (unsigned short*)(ws + off); off += (size_t)DC * DC * 2; // 2 MB
    unsigned short* Tm = (unsigned short*)(ws + off); off += nElem * 2;       // 32 MB
    unsigned* cand = (unsigned*)(ws + off); off += (size_t)BC * 16 * CAP * 4; // 2 MB
    unsigned* cnt  = (unsigned*)(ws + off); off += (size_t)BC * 16 * 4;

    int n4 = (int)(nElem / 4);
    cast_bf16_kernel<<<n4 / 256, 256, 0, stream>>>(in1, A1, n4);
    cast_bf16_kernel<<<n4 / 256, 256, 0, stream>>>(in2, A2, n4);
    transpose_cast_kernel<<<dim3(DC / 32, DC / 32), dim3(32, 8), 0, stream>>>(W, Wt);
    init_kernel<<<2, 256, 0, stream>>>(cnt);

    gemm1_kernel<<<dim3(128, 8), 256, 0, stream>>>(A1, Wt, Tm);
    gemm2_kernel<<<dim3(4, 4, BC), 256, 0, stream>>>(Tm, A2, mask1, mask2, bias,
                                                     cand, cnt);
    final_kernel<<<BC, 256, 0, stream>>>(cand, cnt, out);
}

// Round 4
// 292.163 us; speedup vs baseline: 1.2292x; 1.2292x over previous
//
#include <hip/hip_runtime.h>

typedef __bf16 bf16_t;
typedef bf16_t bf16x8 __attribute__((ext_vector_type(8)));
typedef float floatx4 __attribute__((ext_vector_type(4)));

#define L1C 512
#define L2C 512
#define BC  32
#define DC  1024
#define KTOP 256
#define NBIN 4096           // 12-bit bins: sign+exp+3 mantissa bits
#define CAP  1024           // per-block candidate slots
#define FBUF 16384          // final-stage LDS candidate buffer (= 16*CAP)

__device__ __forceinline__ unsigned short f2bf(float f) {
    unsigned u = __float_as_uint(f);
    u += 0x7FFFu + ((u >> 16) & 1u);   // RNE (data has no NaNs)
    return (unsigned short)(u >> 16);
}

// async global->LDS, 16B per lane; LDS dest = wave-uniform base + lane*16
__device__ __forceinline__ void g2l16(const unsigned short* g, unsigned short* l) {
    __builtin_amdgcn_global_load_lds((const unsigned int*)g, (unsigned int*)l,
                                     16, 0, 0);
}

__device__ __forceinline__ float decode_key(unsigned k) {
    return __uint_as_float(k & 0x7FFFFFFFu);
}

// ---------------- cast f32 -> bf16 (x4 vectorized) ----------------
__global__ void cast_bf16_kernel(const float* __restrict__ src,
                                 unsigned short* __restrict__ dst, int n4) {
    int i = blockIdx.x * blockDim.x + threadIdx.x;
    if (i < n4) {
        float4 v = reinterpret_cast<const float4*>(src)[i];
        ushort4 o;
        o.x = f2bf(v.x); o.y = f2bf(v.y); o.z = f2bf(v.z); o.w = f2bf(v.w);
        reinterpret_cast<ushort4*>(dst)[i] = o;
    }
}

// ---------------- W[d][e] -> Wt[e][d], bf16 ----------------
__global__ void transpose_cast_kernel(const float* __restrict__ W,
                                      unsigned short* __restrict__ Wt) {
    __shared__ float tile[32][33];
    int d0 = blockIdx.x * 32, e0 = blockIdx.y * 32;
    int tx = threadIdx.x;
    for (int i = threadIdx.y; i < 32; i += 8)
        tile[i][tx] = W[(size_t)(d0 + i) * DC + e0 + tx];
    __syncthreads();
    for (int i = threadIdx.y; i < 32; i += 8)
        Wt[(size_t)(e0 + i) * DC + d0 + tx] = f2bf(tile[tx][i]);
}

// ---------------- zero per-block candidate counters ----------------
__global__ void init_kernel(unsigned* __restrict__ cnt) {
    int gid = blockIdx.x * blockDim.x + threadIdx.x;
    if (gid < BC * 16) cnt[gid] = 0;
}

// ---------------- GEMM1: T[r][e] = sum_d A1[r][d] * Wt[e][d], bf16 out ----
__global__ __launch_bounds__(256) void gemm1_kernel(
    const unsigned short* __restrict__ A,    // [16384,1024] bf16
    const unsigned short* __restrict__ Bt,   // [1024,1024]  bf16 (Wt)
    unsigned short* __restrict__ C) {        // [16384,1024] bf16
    __shared__ unsigned short As[128][32];
    __shared__ unsigned short Bs[128][32];
    int tid = threadIdx.x;
    int wave = tid >> 6, lane = tid & 63;
    int lane15 = lane & 15, quad = lane >> 4;
    int wm = wave >> 1, wn = wave & 1;
    size_t m0 = (size_t)blockIdx.x * 128, n0 = (size_t)blockIdx.y * 128;

    floatx4 zero = {0.f, 0.f, 0.f, 0.f};
    floatx4 acc[4][4];
#pragma unroll
    for (int i = 0; i < 4; i++)
#pragma unroll
        for (int j = 0; j < 4; j++) acc[i][j] = zero;

    for (int k0 = 0; k0 < DC; k0 += 32) {
#pragma unroll
        for (int c = 0; c < 2; c++) {
            int cid = c * 256 + tid;
            int row = cid >> 2, col8 = (cid & 3) * 8;
            unsigned short* lbase = &As[0][0] + (c * 256 + wave * 64) * 8;
            g2l16(&A[(m0 + row) * DC + k0 + col8], lbase);
            unsigned short* lbase2 = &Bs[0][0] + (c * 256 + wave * 64) * 8;
            g2l16(&Bt[(n0 + row) * DC + k0 + col8], lbase2);
        }
        __syncthreads();
        bf16x8 af[4], bfr[4];
#pragma unroll
        for (int mi = 0; mi < 4; mi++)
            af[mi] = *reinterpret_cast<const bf16x8*>(&As[wm * 64 + mi * 16 + lane15][quad * 8]);
#pragma unroll
        for (int ni = 0; ni < 4; ni++)
            bfr[ni] = *reinterpret_cast<const bf16x8*>(&Bs[wn * 64 + ni * 16 + lane15][quad * 8]);
#pragma unroll
        for (int mi = 0; mi < 4; mi++)
#pragma unroll
            for (int ni = 0; ni < 4; ni++)
                acc[mi][ni] = __builtin_amdgcn_mfma_f32_16x16x32_bf16(
                    af[mi], bfr[ni], acc[mi][ni], 0, 0, 0);
        __syncthreads();
    }
#pragma unroll
    for (int mi = 0; mi < 4; mi++)
#pragma unroll
        for (int ni = 0; ni < 4; ni++)
#pragma unroll
            for (int r = 0; r < 4; r++) {
                size_t row = m0 + wm * 64 + mi * 16 + quad * 4 + r;
                size_t col = n0 + wn * 64 + ni * 16 + lane15;
                C[row * DC + col] = f2bf(acc[mi][ni][r]);
            }
}

// ---- GEMM2: S = relu(T_b @ H2_b^T + bias); emit block-local top-k cands ---
__global__ __launch_bounds__(256) void gemm2_kernel(
    const unsigned short* __restrict__ Tm,   // [16384,1024] bf16
    const unsigned short* __restrict__ H2,   // [16384,1024] bf16 (inputs2 layout)
    const int* __restrict__ mask1, const int* __restrict__ mask2,
    const float* __restrict__ bptr,
    unsigned* __restrict__ cand,             // [32*16][CAP]
    unsigned* __restrict__ cnt) {            // [32*16]
    __shared__ unsigned short As[128][32];
    __shared__ unsigned short Bs[128][32];
    __shared__ unsigned lh[NBIN];
    __shared__ unsigned csum[256];
    __shared__ int m1s[128], m2s[128];
    __shared__ unsigned tsh, lcnt;
    int tid = threadIdx.x;
    int wave = tid >> 6, lane = tid & 63;
    int lane15 = lane & 15, quad = lane >> 4;
    int wm = wave >> 1, wn = wave & 1;
    int m0 = blockIdx.x * 128, n0 = blockIdx.y * 128;
    int b = blockIdx.z;
    int gblk = b * 16 + blockIdx.y * 4 + blockIdx.x;
    const size_t ldr = (size_t)BC * DC;      // 32768 row stride
    const unsigned short* Ab = Tm + (size_t)b * DC;
    const unsigned short* Bb = H2 + (size_t)b * DC;

    for (int i = tid; i < NBIN; i += 256) lh[i] = 0;
    if (tid < 128) m1s[tid] = (mask1[(m0 + tid) * BC + b] == 0);
    else           m2s[tid - 128] = (mask2[(n0 + tid - 128) * BC + b] == 0);

    floatx4 zero = {0.f, 0.f, 0.f, 0.f};
    floatx4 acc[4][4];
#pragma unroll
    for (int i = 0; i < 4; i++)
#pragma unroll
        for (int j = 0; j < 4; j++) acc[i][j] = zero;

    for (int k0 = 0; k0 < DC; k0 += 32) {
#pragma unroll
        for (int c = 0; c < 2; c++) {
            int cid = c * 256 + tid;
            int row = cid >> 2, col8 = (cid & 3) * 8;
            unsigned short* lbase = &As[0][0] + (c * 256 + wave * 64) * 8;
            g2l16(&Ab[(size_t)(m0 + row) * ldr + k0 + col8], lbase);
            unsigned short* lbase2 = &Bs[0][0] + (c * 256 + wave * 64) * 8;
            g2l16(&Bb[(size_t)(n0 + row) * ldr + k0 + col8], lbase2);
        }
        __syncthreads();
        bf16x8 af[4], bfr[4];
#pragma unroll
        for (int mi = 0; mi < 4; mi++)
            af[mi] = *reinterpret_cast<const bf16x8*>(&As[wm * 64 + mi * 16 + lane15][quad * 8]);
#pragma unroll
        for (int ni = 0; ni < 4; ni++)
            bfr[ni] = *reinterpret_cast<const bf16x8*>(&Bs[wn * 64 + ni * 16 + lane15][quad * 8]);
#pragma unroll
        for (int mi = 0; mi < 4; mi++)
#pragma unroll
            for (int ni = 0; ni < 4; ni++)
                acc[mi][ni] = __builtin_amdgcn_mfma_f32_16x16x32_bf16(
                    af[mi], bfr[ni], acc[mi][ni], 0, 0, 0);
        __syncthreads();
    }

    float bias = bptr[0];
    // pass 1: local 4096-bin histogram of valid keys (zeros counted privately
    // to avoid same-address LDS atomic storms on the zero bin)
    unsigned zc = 0;
#pragma unroll
    for (int ni = 0; ni < 4; ni++) {
        int jl = wn * 64 + ni * 16 + lane15;
        int v2 = m2s[jl];
#pragma unroll
        for (int mi = 0; mi < 4; mi++)
#pragma unroll
            for (int r = 0; r < 4; r++) {
                int il = wm * 64 + mi * 16 + quad * 4 + r;
                float s = acc[mi][ni][r] + bias;
                if (v2 && m1s[il]) {
                    if (s > 0.f)
                        atomicAdd(&lh[(__float_as_uint(s) | 0x80000000u) >> 20], 1u);
                    else
                        zc++;
                }
            }
    }
    if (zc) atomicAdd(&lh[2048], zc);
    __syncthreads();
    unsigned s16 = 0;
#pragma unroll
    for (int i = 0; i < 16; i++) s16 += lh[tid * 16 + i];
    csum[tid] = s16;
    __syncthreads();
    if (tid == 0) {
        unsigned cum = 0, bin = 2048;
        int found = 0;
        for (int c = 255; c >= 128 && !found; --c) {
            unsigned cs = csum[c];
            if (cum + cs >= KTOP) {
                for (int bb = c * 16 + 15; bb >= c * 16; --bb) {
                    unsigned h = lh[bb];
                    if (cum + h >= KTOP) { bin = (unsigned)bb; found = 1; break; }
                    cum += h;
                }
            } else cum += cs;
        }
        tsh = bin << 20;
        lcnt = 0;
    }
    __syncthreads();
    // pass 2: emit keys >= block-local threshold
    unsigned T = tsh;
    unsigned base = (unsigned)gblk * CAP;
#pragma unroll
    for (int ni = 0; ni < 4; ni++) {
        int jl = wn * 64 + ni * 16 + lane15;
        int v2 = m2s[jl];
#pragma unroll
        for (int mi = 0; mi < 4; mi++)
#pragma unroll
            for (int r = 0; r < 4; r++) {
                int il = wm * 64 + mi * 16 + quad * 4 + r;
                float s = acc[mi][ni][r] + bias;
                s = s > 0.f ? s : 0.f;
                unsigned key = (v2 && m1s[il])
                                   ? (__float_as_uint(s) | 0x80000000u) : 0u;
                if (key >= T) {
                    unsigned p = atomicAdd(&lcnt, 1u);
                    if (p < CAP) cand[base + p] = key;
                }
            }
    }
    __syncthreads();
    if (tid == 0) cnt[gblk] = lcnt < CAP ? lcnt : CAP;
}

// ---- final: per batch, EXACT top-256 via 3-pass LDS radix select ----
// 1024 threads (16 waves) for latency hiding; candidates staged in LDS once.
__global__ __launch_bounds__(1024) void final_kernel(
    const unsigned* __restrict__ cand, const unsigned* __restrict__ cnt,
    float* __restrict__ out) {
    __shared__ unsigned buf[FBUF];     // 64 KB
    __shared__ unsigned h[NBIN];       // 16 KB
    __shared__ unsigned ss[256];       // suffix sums over chunks
    __shared__ unsigned scnt_s[16], off_s[16];
    __shared__ unsigned ntot_s, sel_c, sel_a, B_s, R_s, mcount;
    __shared__ int have_s;
    __shared__ unsigned srt[256];
    int b = blockIdx.x, tid = threadIdx.x;

    if (tid < 16) {
        unsigned c = cnt[b * 16 + tid];
        scnt_s[tid] = c < CAP ? c : CAP;
    }
    __syncthreads();
    if (tid == 0) {
        unsigned o = 0;
        for (int i = 0; i < 16; i++) { off_s[i] = o; o += scnt_s[i]; }
        ntot_s = o;
        have_s = 1;
    }
    __syncthreads();
    // stage all candidates into LDS
    for (int blk = 0; blk < 16; blk++) {
        unsigned c = scnt_s[blk], o = off_s[blk];
        const unsigned* p = cand + (size_t)(b * 16 + blk) * CAP;
        for (unsigned i = tid; i < c; i += 1024) buf[o + i] = p[i];
    }
    __syncthreads();
    unsigned n = ntot_s;

    // 3-pass radix select: find exact 256th-largest key
    unsigned Kr = KTOP;      // rank target within current prefix class
    unsigned pfx = 0;        // accumulated high-bit prefix (uniform)
    unsigned kth = 0;
    for (int pass = 0; pass < 3; pass++) {
        int bins = (pass < 2) ? NBIN : 256;
        int shift = (pass == 0) ? 20 : (pass == 1) ? 8 : 0;
        int nch = bins >> 4;
        for (int i = tid; i < bins; i += 1024) h[i] = 0;
        __syncthreads();
        for (unsigned i = tid; i < n; i += 1024) {
            unsigned k = buf[i];
            bool ok = (pass == 0) ||
                      (pass == 1 && (k >> 20) == pfx) ||
                      (pass == 2 && (k >> 8) == pfx);
            if (ok) atomicAdd(&h[(k >> shift) & (bins - 1)], 1u);
        }
        __syncthreads();
        if (tid < nch) {
            unsigned s = 0;
#pragma unroll
            for (int i = 0; i < 16; i++) s += h[tid * 16 + i];
            ss[tid] = s;
        }
        __syncthreads();
        for (int off = 1; off < nch; off <<= 1) {
            unsigned v = 0;
            if (tid < nch && tid + (unsigned)off < (unsigned)nch) v = ss[tid + off];
            __syncthreads();
            if (tid < nch) ss[tid] += v;
            __syncthreads();
        }
        if (pass == 0) {
            if (tid == 0) have_s = (ss[0] >= KTOP);
            __syncthreads();
            if (!have_s) break;           // fewer than k candidates total
        }
        if (tid < nch) {
            unsigned above = (tid + 1 < (unsigned)nch) ? ss[tid + 1] : 0u;
            if (above < Kr && ss[tid] >= Kr) { sel_c = tid; sel_a = above; }
        }
        __syncthreads();
        if (tid == 0) {
            unsigned cum = sel_a;
            for (int bb = (int)sel_c * 16 + 15; bb >= (int)sel_c * 16; --bb) {
                unsigned hb = h[bb];
                if (cum + hb >= Kr) { B_s = (unsigned)bb; R_s = Kr - cum; break; }
                cum += hb;
            }
        }
        __syncthreads();
        unsigned Bv = B_s;
        Kr = R_s;
        if (pass == 0) pfx = Bv;
        else if (pass == 1) pfx = (pfx << 12) | Bv;
        else kth = (pfx << 8) | Bv;
        __syncthreads();
    }

    // compact keys strictly greater than kth (have) or all keys (!have)
    if (tid == 0) mcount = 0;
    __syncthreads();
    int have = have_s;
    unsigned lim = have ? kth : 0u;
    for (unsigned i = tid; i < n; i += 1024) {
        unsigned k = buf[i];
        if (k > lim) {
            unsigned p = atomicAdd(&mcount, 1u);
            if (p < 256) srt[p] = k;
        }
    }
    __syncthreads();
    unsigned m = mcount;
    if (tid < 256 && tid >= (int)m) srt[tid] = have ? kth : 0u;
    // bitonic sort 256 descending
    for (int k2 = 2; k2 <= 256; k2 <<= 1) {
        for (int j2 = k2 >> 1; j2 > 0; j2 >>= 1) {
            __syncthreads();
            if (tid < 256) {
                int ixj = tid ^ j2;
                if (ixj > tid) {
                    unsigned a = srt[tid], c = srt[ixj];
                    bool up = (tid & k2) == 0;
                    if (up ? (a < c) : (a > c)) { srt[tid] = c; srt[ixj] = a; }
                }
            }
        }
    }
    __syncthreads();
    if (tid < 256) {
        unsigned nval = have ? KTOP : (m < KTOP ? m : KTOP);
        float v;
        if ((unsigned)tid < nval) v = decode_key(srt[tid]);
        else v = (nval > 0) ? decode_key(srt[nval - 1]) : -__builtin_inff();
        out[b * KTOP + tid] = v;
    }
}

// ---------------- launch ----------------
extern "C" void kernel_launch(void* const* d_in, const int* in_sizes, int n_in,
                              void* d_out, int out_size, void* d_ws, size_t ws_size,
                              hipStream_t stream) {
    const float* in1   = (const float*)d_in[0];   // [512,32,1024]
    const float* in2   = (const float*)d_in[1];   // [512,32,1024]
    const int*   mask1 = (const int*)d_in[2];     // [512,32]
    const int*   mask2 = (const int*)d_in[3];     // [512,32]
    const float* W     = (const float*)d_in[4];   // [1024,1024]
    const float* bias  = (const float*)d_in[5];   // [1]
    float* out = (float*)d_out;

    char* ws = (char*)d_ws;
    size_t off = 0;
    const size_t nElem = (size_t)L1C * BC * DC;       // 16777216
    unsigned short* A1 = (unsigned short*)(ws + off); off += nElem * 2;       // 32 MB
    unsigned short* A2 = (unsigned short*)(ws + off); off += nElem * 2;       // 32 MB
    unsigned short* Wt = (unsigned short*)(ws + off); off += (size_t)DC * DC * 2; // 2 MB
    unsigned short* Tm = (unsigned short*)(ws + off); off += nElem * 2;       // 32 MB
    unsigned* cand = (unsigned*)(ws + off); off += (size_t)BC * 16 * CAP * 4; // 2 MB
    unsigned* cnt  = (unsigned*)(ws + off); off += (size_t)BC * 16 * 4;

    int n4 = (int)(nElem / 4);
    cast_bf16_kernel<<<n4 / 256, 256, 0, stream>>>(in1, A1, n4);
    cast_bf16_kernel<<<n4 / 256, 256, 0, stream>>>(in2, A2, n4);
    transpose_cast_kernel<<<dim3(DC / 32, DC / 32), dim3(32, 8), 0, stream>>>(W, Wt);
    init_kernel<<<2, 256, 0, stream>>>(cnt);

    gemm1_kernel<<<dim3(128, 8), 256, 0, stream>>>(A1, Wt, Tm);
    gemm2_kernel<<<dim3(4, 4, BC), 256, 0, stream>>>(Tm, A2, mask1, mask2, bias,
                                                     cand, cnt);
    final_kernel<<<BC, 1024, 0, stream>>>(cand, cnt, out);
}

// Round 5
// 281.106 us; speedup vs baseline: 1.2776x; 1.0393x over previous
//
#include <hip/hip_runtime.h>

typedef __bf16 bf16_t;
typedef bf16_t bf16x8 __attribute__((ext_vector_type(8)));
typedef float floatx4 __attribute__((ext_vector_type(4)));

#define L1C 512
#define L2C 512
#define BC  32
#define DC  1024
#define KTOP 256
#define NBIN 4096           // 12-bit bins: sign+exp+3 mantissa bits
#define CAP  1024           // per-block candidate slots
#define FBUF 16384          // final-stage LDS candidate buffer (= 16*CAP)

__device__ __forceinline__ unsigned short f2bf(float f) {
    unsigned u = __float_as_uint(f);
    u += 0x7FFFu + ((u >> 16) & 1u);   // RNE (data has no NaNs)
    return (unsigned short)(u >> 16);
}

// async global->LDS, 16B per lane; LDS dest = wave-uniform base + lane*16
__device__ __forceinline__ void g2l16(const unsigned short* g, unsigned short* l) {
    __builtin_amdgcn_global_load_lds((const unsigned int*)g, (unsigned int*)l,
                                     16, 0, 0);
}

__device__ __forceinline__ float decode_key(unsigned k) {
    return __uint_as_float(k & 0x7FFFFFFFu);
}

// ---- fused transposing cast: [L,B,D] f32 -> [B,L,D] bf16, both inputs ----
// one block per source row (l,b); 256 thr x float4 = 1024 elems
__global__ __launch_bounds__(256) void cast_tr_kernel(
    const float* __restrict__ in1, const float* __restrict__ in2,
    unsigned short* __restrict__ A1, unsigned short* __restrict__ A2) {
    int r = blockIdx.x;
    const float* src;
    unsigned short* dst;
    if (r < L1C * BC) {
        int l = r >> 5, b = r & 31;
        src = in1 + (size_t)r * DC;
        dst = A1 + ((size_t)b * L1C + l) * DC;
    } else {
        int r2 = r - L1C * BC;
        int l = r2 >> 5, b = r2 & 31;
        src = in2 + (size_t)r2 * DC;
        dst = A2 + ((size_t)b * L2C + l) * DC;
    }
    int t = threadIdx.x;
    float4 v = reinterpret_cast<const float4*>(src)[t];
    ushort4 o;
    o.x = f2bf(v.x); o.y = f2bf(v.y); o.z = f2bf(v.z); o.w = f2bf(v.w);
    reinterpret_cast<ushort4*>(dst)[t] = o;
}

// ---------------- W[d][e] -> Wt[e][d], bf16 ----------------
__global__ void transpose_cast_kernel(const float* __restrict__ W,
                                      unsigned short* __restrict__ Wt) {
    __shared__ float tile[32][33];
    int d0 = blockIdx.x * 32, e0 = blockIdx.y * 32;
    int tx = threadIdx.x;
    for (int i = threadIdx.y; i < 32; i += 8)
        tile[i][tx] = W[(size_t)(d0 + i) * DC + e0 + tx];
    __syncthreads();
    for (int i = threadIdx.y; i < 32; i += 8)
        Wt[(size_t)(e0 + i) * DC + d0 + tx] = f2bf(tile[tx][i]);
}

// ---- init: zero counters + transpose masks [L,B]->[B,L] ----
__global__ void init_kernel(const int* __restrict__ mask1,
                            const int* __restrict__ mask2,
                            int* __restrict__ m1t, int* __restrict__ m2t,
                            unsigned* __restrict__ cnt) {
    int gid = blockIdx.x * blockDim.x + threadIdx.x;
    if (gid < L1C * BC) {
        int l = gid & 511, b = gid >> 9;
        m1t[gid] = mask1[(l << 5) + b];
        m2t[gid] = mask2[(l << 5) + b];
    }
    if (gid < BC * 16) cnt[gid] = 0;
}

// ---------------- GEMM1: T[r][e] = sum_d A1[r][d] * Wt[e][d], bf16 out ----
__global__ __launch_bounds__(256) void gemm1_kernel(
    const unsigned short* __restrict__ A,    // [16384,1024] bf16 (batch-major)
    const unsigned short* __restrict__ Bt,   // [1024,1024]  bf16 (Wt)
    unsigned short* __restrict__ C) {        // [16384,1024] bf16 (batch-major)
    __shared__ unsigned short As[128][32];
    __shared__ unsigned short Bs[128][32];
    int tid = threadIdx.x;
    int wave = tid >> 6, lane = tid & 63;
    int lane15 = lane & 15, quad = lane >> 4;
    int wm = wave >> 1, wn = wave & 1;
    size_t m0 = (size_t)blockIdx.x * 128, n0 = (size_t)blockIdx.y * 128;

    floatx4 zero = {0.f, 0.f, 0.f, 0.f};
    floatx4 acc[4][4];
#pragma unroll
    for (int i = 0; i < 4; i++)
#pragma unroll
        for (int j = 0; j < 4; j++) acc[i][j] = zero;

    for (int k0 = 0; k0 < DC; k0 += 32) {
#pragma unroll
        for (int c = 0; c < 2; c++) {
            int cid = c * 256 + tid;
            int row = cid >> 2, col8 = (cid & 3) * 8;
            unsigned short* lbase = &As[0][0] + (c * 256 + wave * 64) * 8;
            g2l16(&A[(m0 + row) * DC + k0 + col8], lbase);
            unsigned short* lbase2 = &Bs[0][0] + (c * 256 + wave * 64) * 8;
            g2l16(&Bt[(n0 + row) * DC + k0 + col8], lbase2);
        }
        __syncthreads();
        bf16x8 af[4], bfr[4];
#pragma unroll
        for (int mi = 0; mi < 4; mi++)
            af[mi] = *reinterpret_cast<const bf16x8*>(&As[wm * 64 + mi * 16 + lane15][quad * 8]);
#pragma unroll
        for (int ni = 0; ni < 4; ni++)
            bfr[ni] = *reinterpret_cast<const bf16x8*>(&Bs[wn * 64 + ni * 16 + lane15][quad * 8]);
#pragma unroll
        for (int mi = 0; mi < 4; mi++)
#pragma unroll
            for (int ni = 0; ni < 4; ni++)
                acc[mi][ni] = __builtin_amdgcn_mfma_f32_16x16x32_bf16(
                    af[mi], bfr[ni], acc[mi][ni], 0, 0, 0);
        __syncthreads();
    }
#pragma unroll
    for (int mi = 0; mi < 4; mi++)
#pragma unroll
        for (int ni = 0; ni < 4; ni++)
#pragma unroll
            for (int r = 0; r < 4; r++) {
                size_t row = m0 + wm * 64 + mi * 16 + quad * 4 + r;
                size_t col = n0 + wn * 64 + ni * 16 + lane15;
                C[row * DC + col] = f2bf(acc[mi][ni][r]);
            }
}

// ---- GEMM2: S = relu(T_b @ H2_b^T + bias); emit block-local top-k cands ---
// batch-major inputs; XCD-swizzled 1D grid (512 blocks)
__global__ __launch_bounds__(256) void gemm2_kernel(
    const unsigned short* __restrict__ Tm,   // [32][512][1024] bf16
    const unsigned short* __restrict__ H2,   // [32][512][1024] bf16
    const int* __restrict__ m1t, const int* __restrict__ m2t,  // [32][512]
    const float* __restrict__ bptr,
    unsigned* __restrict__ cand,             // [32*16][CAP]
    unsigned* __restrict__ cnt) {            // [32*16]
    __shared__ unsigned short As[128][32];
    __shared__ unsigned short Bs[128][32];
    __shared__ unsigned lh[NBIN];
    __shared__ unsigned csum[256];
    __shared__ int m1s[128], m2s[128];
    __shared__ unsigned tsh, lcnt;
    int tid = threadIdx.x;
    int wave = tid >> 6, lane = tid & 63;
    int lane15 = lane & 15, quad = lane >> 4;
    int wm = wave >> 1, wn = wave & 1;
    // XCD swizzle: all 16 tiles of one batch share (linear id % 8) -> same XCD
    int L = blockIdx.x;
    int xcd = L & 7, tile = (L >> 3) & 15, chunk = L >> 7;
    int b = xcd + (chunk << 3);
    int bx = tile & 3, by = tile >> 2;
    int m0 = bx * 128, n0 = by * 128;
    int gblk = b * 16 + by * 4 + bx;
    const unsigned short* Ab = Tm + (size_t)b * L1C * DC;
    const unsigned short* Bb = H2 + (size_t)b * L2C * DC;

    for (int i = tid; i < NBIN; i += 256) lh[i] = 0;
    if (tid < 128) m1s[tid] = (m1t[b * L1C + m0 + tid] == 0);
    else           m2s[tid - 128] = (m2t[b * L2C + n0 + tid - 128] == 0);

    floatx4 zero = {0.f, 0.f, 0.f, 0.f};
    floatx4 acc[4][4];
#pragma unroll
    for (int i = 0; i < 4; i++)
#pragma unroll
        for (int j = 0; j < 4; j++) acc[i][j] = zero;

    for (int k0 = 0; k0 < DC; k0 += 32) {
#pragma unroll
        for (int c = 0; c < 2; c++) {
            int cid = c * 256 + tid;
            int row = cid >> 2, col8 = (cid & 3) * 8;
            unsigned short* lbase = &As[0][0] + (c * 256 + wave * 64) * 8;
            g2l16(&Ab[(size_t)(m0 + row) * DC + k0 + col8], lbase);
            unsigned short* lbase2 = &Bs[0][0] + (c * 256 + wave * 64) * 8;
            g2l16(&Bb[(size_t)(n0 + row) * DC + k0 + col8], lbase2);
        }
        __syncthreads();
        bf16x8 af[4], bfr[4];
#pragma unroll
        for (int mi = 0; mi < 4; mi++)
            af[mi] = *reinterpret_cast<const bf16x8*>(&As[wm * 64 + mi * 16 + lane15][quad * 8]);
#pragma unroll
        for (int ni = 0; ni < 4; ni++)
            bfr[ni] = *reinterpret_cast<const bf16x8*>(&Bs[wn * 64 + ni * 16 + lane15][quad * 8]);
#pragma unroll
        for (int mi = 0; mi < 4; mi++)
#pragma unroll
            for (int ni = 0; ni < 4; ni++)
                acc[mi][ni] = __builtin_amdgcn_mfma_f32_16x16x32_bf16(
                    af[mi], bfr[ni], acc[mi][ni], 0, 0, 0);
        __syncthreads();
    }

    float bias = bptr[0];
    // pass 1: local 4096-bin histogram of valid keys (zeros counted privately
    // to avoid same-address LDS atomic storms on the zero bin)
    unsigned zc = 0;
#pragma unroll
    for (int ni = 0; ni < 4; ni++) {
        int jl = wn * 64 + ni * 16 + lane15;
        int v2 = m2s[jl];
#pragma unroll
        for (int mi = 0; mi < 4; mi++)
#pragma unroll
            for (int r = 0; r < 4; r++) {
                int il = wm * 64 + mi * 16 + quad * 4 + r;
                float s = acc[mi][ni][r] + bias;
                if (v2 && m1s[il]) {
                    if (s > 0.f)
                        atomicAdd(&lh[(__float_as_uint(s) | 0x80000000u) >> 20], 1u);
                    else
                        zc++;
                }
            }
    }
    if (zc) atomicAdd(&lh[2048], zc);
    __syncthreads();
    unsigned s16 = 0;
#pragma unroll
    for (int i = 0; i < 16; i++) s16 += lh[tid * 16 + i];
    csum[tid] = s16;
    __syncthreads();
    if (tid == 0) {
        unsigned cum = 0, bin = 2048;
        int found = 0;
        for (int c = 255; c >= 128 && !found; --c) {
            unsigned cs = csum[c];
            if (cum + cs >= KTOP) {
                for (int bb = c * 16 + 15; bb >= c * 16; --bb) {
                    unsigned h = lh[bb];
                    if (cum + h >= KTOP) { bin = (unsigned)bb; found = 1; break; }
                    cum += h;
                }
            } else cum += cs;
        }
        tsh = bin << 20;
        lcnt = 0;
    }
    __syncthreads();
    // pass 2: emit keys >= block-local threshold
    unsigned T = tsh;
    unsigned base = (unsigned)gblk * CAP;
#pragma unroll
    for (int ni = 0; ni < 4; ni++) {
        int jl = wn * 64 + ni * 16 + lane15;
        int v2 = m2s[jl];
#pragma unroll
        for (int mi = 0; mi < 4; mi++)
#pragma unroll
            for (int r = 0; r < 4; r++) {
                int il = wm * 64 + mi * 16 + quad * 4 + r;
                float s = acc[mi][ni][r] + bias;
                s = s > 0.f ? s : 0.f;
                unsigned key = (v2 && m1s[il])
                                   ? (__float_as_uint(s) | 0x80000000u) : 0u;
                if (key >= T) {
                    unsigned p = atomicAdd(&lcnt, 1u);
                    if (p < CAP) cand[base + p] = key;
                }
            }
    }
    __syncthreads();
    if (tid == 0) cnt[gblk] = lcnt < CAP ? lcnt : CAP;
}

// ---- final: per batch, EXACT top-256 via 3-pass LDS radix select ----
__global__ __launch_bounds__(1024) void final_kernel(
    const unsigned* __restrict__ cand, const unsigned* __restrict__ cnt,
    float* __restrict__ out) {
    __shared__ unsigned buf[FBUF];     // 64 KB
    __shared__ unsigned h[NBIN];       // 16 KB
    __shared__ unsigned ss[256];       // suffix sums over chunks
    __shared__ unsigned scnt_s[16], off_s[16];
    __shared__ unsigned ntot_s, sel_c, sel_a, B_s, R_s, mcount;
    __shared__ int have_s;
    __shared__ unsigned srt[256];
    int b = blockIdx.x, tid = threadIdx.x;

    if (tid < 16) {
        unsigned c = cnt[b * 16 + tid];
        scnt_s[tid] = c < CAP ? c : CAP;
    }
    __syncthreads();
    if (tid == 0) {
        unsigned o = 0;
        for (int i = 0; i < 16; i++) { off_s[i] = o; o += scnt_s[i]; }
        ntot_s = o;
        have_s = 1;
    }
    __syncthreads();
    for (int blk = 0; blk < 16; blk++) {
        unsigned c = scnt_s[blk], o = off_s[blk];
        const unsigned* p = cand + (size_t)(b * 16 + blk) * CAP;
        for (unsigned i = tid; i < c; i += 1024) buf[o + i] = p[i];
    }
    __syncthreads();
    unsigned n = ntot_s;

    unsigned Kr = KTOP;
    unsigned pfx = 0;
    unsigned kth = 0;
    for (int pass = 0; pass < 3; pass++) {
        int bins = (pass < 2) ? NBIN : 256;
        int shift = (pass == 0) ? 20 : (pass == 1) ? 8 : 0;
        int nch = bins >> 4;
        for (int i = tid; i < bins; i += 1024) h[i] = 0;
        __syncthreads();
        for (unsigned i = tid; i < n; i += 1024) {
            unsigned k = buf[i];
            bool ok = (pass == 0) ||
                      (pass == 1 && (k >> 20) == pfx) ||
                      (pass == 2 && (k >> 8) == pfx);
            if (ok) atomicAdd(&h[(k >> shift) & (bins - 1)], 1u);
        }
        __syncthreads();
        if (tid < nch) {
            unsigned s = 0;
#pragma unroll
            for (int i = 0; i < 16; i++) s += h[tid * 16 + i];
            ss[tid] = s;
        }
        __syncthreads();
        for (int off = 1; off < nch; off <<= 1) {
            unsigned v = 0;
            if (tid < nch && tid + (unsigned)off < (unsigned)nch) v = ss[tid + off];
            __syncthreads();
            if (tid < nch) ss[tid] += v;
            __syncthreads();
        }
        if (pass == 0) {
            if (tid == 0) have_s = (ss[0] >= KTOP);
            __syncthreads();
            if (!have_s) break;
        }
        if (tid < nch) {
            unsigned above = (tid + 1 < (unsigned)nch) ? ss[tid + 1] : 0u;
            if (above < Kr && ss[tid] >= Kr) { sel_c = tid; sel_a = above; }
        }
        __syncthreads();
        if (tid == 0) {
            unsigned cum = sel_a;
            for (int bb = (int)sel_c * 16 + 15; bb >= (int)sel_c * 16; --bb) {
                unsigned hb = h[bb];
                if (cum + hb >= Kr) { B_s = (unsigned)bb; R_s = Kr - cum; break; }
                cum += hb;
            }
        }
        __syncthreads();
        unsigned Bv = B_s;
        Kr = R_s;
        if (pass == 0) pfx = Bv;
        else if (pass == 1) pfx = (pfx << 12) | Bv;
        else kth = (pfx << 8) | Bv;
        __syncthreads();
    }

    if (tid == 0) mcount = 0;
    __syncthreads();
    int have = have_s;
    unsigned lim = have ? kth : 0u;
    for (unsigned i = tid; i < n; i += 1024) {
        unsigned k = buf[i];
        if (k > lim) {
            unsigned p = atomicAdd(&mcount, 1u);
            if (p < 256) srt[p] = k;
        }
    }
    __syncthreads();
    unsigned m = mcount;
    if (tid < 256 && tid >= (int)m) srt[tid] = have ? kth : 0u;
    for (int k2 = 2; k2 <= 256; k2 <<= 1) {
        for (int j2 = k2 >> 1; j2 > 0; j2 >>= 1) {
            __syncthreads();
            if (tid < 256) {
                int ixj = tid ^ j2;
                if (ixj > tid) {
                    unsigned a = srt[tid], c = srt[ixj];
                    bool up = (tid & k2) == 0;
                    if (up ? (a < c) : (a > c)) { srt[tid] = c; srt[ixj] = a; }
                }
            }
        }
    }
    __syncthreads();
    if (tid < 256) {
        unsigned nval = have ? KTOP : (m < KTOP ? m : KTOP);
        float v;
        if ((unsigned)tid < nval) v = decode_key(srt[tid]);
        else v = (nval > 0) ? decode_key(srt[nval - 1]) : -__builtin_inff();
        out[b * KTOP + tid] = v;
    }
}

// ---------------- launch ----------------
extern "C" void kernel_launch(void* const* d_in, const int* in_sizes, int n_in,
                              void* d_out, int out_size, void* d_ws, size_t ws_size,
                              hipStream_t stream) {
    const float* in1   = (const float*)d_in[0];   // [512,32,1024]
    const float* in2   = (const float*)d_in[1];   // [512,32,1024]
    const int*   mask1 = (const int*)d_in[2];     // [512,32]
    const int*   mask2 = (const int*)d_in[3];     // [512,32]
    const float* W     = (const float*)d_in[4];   // [1024,1024]
    const float* bias  = (const float*)d_in[5];   // [1]
    float* out = (float*)d_out;

    char* ws = (char*)d_ws;
    size_t off = 0;
    const size_t nElem = (size_t)L1C * BC * DC;       // 16777216
    unsigned short* A1 = (unsigned short*)(ws + off); off += nElem * 2;       // 32 MB
    unsigned short* A2 = (unsigned short*)(ws + off); off += nElem * 2;       // 32 MB
    unsigned short* Wt = (unsigned short*)(ws + off); off += (size_t)DC * DC * 2; // 2 MB
    unsigned short* Tm = (unsigned short*)(ws + off); off += nElem * 2;       // 32 MB
    unsigned* cand = (unsigned*)(ws + off); off += (size_t)BC * 16 * CAP * 4; // 2 MB
    unsigned* cnt  = (unsigned*)(ws + off); off += (size_t)BC * 16 * 4;
    int* m1t = (int*)(ws + off); off += (size_t)BC * L1C * 4;
    int* m2t = (int*)(ws + off); off += (size_t)BC * L2C * 4;

    cast_tr_kernel<<<2 * L1C * BC, 256, 0, stream>>>(in1, in2, A1, A2);
    transpose_cast_kernel<<<dim3(DC / 32, DC / 32), dim3(32, 8), 0, stream>>>(W, Wt);
    init_kernel<<<64, 256, 0, stream>>>(mask1, mask2, m1t, m2t, cnt);

    gemm1_kernel<<<dim3(128, 8), 256, 0, stream>>>(A1, Wt, Tm);
    gemm2_kernel<<<512, 256, 0, stream>>>(Tm, A2, m1t, m2t, bias, cand, cnt);
    final_kernel<<<BC, 1024, 0, stream>>>(cand, cnt, out);
}

// Round 6
// 275.206 us; speedup vs baseline: 1.3050x; 1.0214x over previous
//
#include <hip/hip_runtime.h>

typedef __bf16 bf16_t;
typedef bf16_t bf16x8 __attribute__((ext_vector_type(8)));
typedef float floatx4 __attribute__((ext_vector_type(4)));

#define L1C 512
#define L2C 512
#define BC  32
#define DC  1024
#define KTOP 256
#define NBIN 4096           // 12-bit bins: sign+exp+3 mantissa bits
#define CAP  1024           // per-block candidate slots
#define FBUF 16384          // final-stage LDS candidate buffer (= 16*CAP)

__device__ __forceinline__ unsigned short f2bf(float f) {
    unsigned u = __float_as_uint(f);
    u += 0x7FFFu + ((u >> 16) & 1u);   // RNE (data has no NaNs)
    return (unsigned short)(u >> 16);
}

// async global->LDS, 16B per lane; LDS dest = wave-uniform base + lane*16
__device__ __forceinline__ void g2l16(const unsigned short* g, unsigned short* l) {
    __builtin_amdgcn_global_load_lds((const unsigned int*)g, (unsigned int*)l,
                                     16, 0, 0);
}

__device__ __forceinline__ float decode_key(unsigned k) {
    return __uint_as_float(k & 0x7FFFFFFFu);
}

// ---- fused prep: transposing casts of in1/in2, W cast, mask transpose ----
// blocks [0,16384): in1 row (l,b) -> A1[b][l][:]
// blocks [16384,32768): in2 row -> A2[b][l][:]
// blocks [32768,33792): W row cast f32->bf16
// blocks [33792,33856): masks [L,B]->[B,L] + cnt zero
__global__ __launch_bounds__(256) void prep_kernel(
    const float* __restrict__ in1, const float* __restrict__ in2,
    const float* __restrict__ W,
    const int* __restrict__ mask1, const int* __restrict__ mask2,
    unsigned short* __restrict__ A1, unsigned short* __restrict__ A2,
    unsigned short* __restrict__ Wb,
    int* __restrict__ m1t, int* __restrict__ m2t,
    unsigned* __restrict__ cnt) {
    int r = blockIdx.x, t = threadIdx.x;
    if (r < 2 * L1C * BC + DC) {
        const float* src;
        unsigned short* dst;
        if (r < L1C * BC) {
            int l = r >> 5, b = r & 31;
            src = in1 + (size_t)r * DC;
            dst = A1 + ((size_t)b * L1C + l) * DC;
        } else if (r < 2 * L1C * BC) {
            int r2 = r - L1C * BC;
            int l = r2 >> 5, b = r2 & 31;
            src = in2 + (size_t)r2 * DC;
            dst = A2 + ((size_t)b * L2C + l) * DC;
        } else {
            int r3 = r - 2 * L1C * BC;
            src = W + (size_t)r3 * DC;
            dst = Wb + (size_t)r3 * DC;
        }
        float4 v = reinterpret_cast<const float4*>(src)[t];
        ushort4 o;
        o.x = f2bf(v.x); o.y = f2bf(v.y); o.z = f2bf(v.z); o.w = f2bf(v.w);
        reinterpret_cast<ushort4*>(dst)[t] = o;
    } else {
        int gid = (r - (2 * L1C * BC + DC)) * 256 + t;   // [0,16384)
        int l = gid & 511, b = gid >> 9;
        m1t[gid] = mask1[(l << 5) + b];
        m2t[gid] = mask2[(l << 5) + b];
        if (gid < BC * 16) cnt[gid] = 0;
    }
}

// ---- GEMM1: V[j][d] = sum_e A2[j][e] * Wb[d][e]  (BK=64) ----
__global__ __launch_bounds__(256) void gemm1_kernel(
    const unsigned short* __restrict__ A,    // [16384,1024] bf16 (A2, batch-major)
    const unsigned short* __restrict__ Bt,   // [1024,1024]  bf16 (Wb = W rows)
    unsigned short* __restrict__ C) {        // [16384,1024] bf16 (V, batch-major)
    __shared__ unsigned short As[128][64];
    __shared__ unsigned short Bs[128][64];
    int tid = threadIdx.x;
    int wave = tid >> 6, lane = tid & 63;
    int lane15 = lane & 15, quad = lane >> 4;
    int wm = wave >> 1, wn = wave & 1;
    size_t m0 = (size_t)blockIdx.x * 128, n0 = (size_t)blockIdx.y * 128;

    floatx4 zero = {0.f, 0.f, 0.f, 0.f};
    floatx4 acc[4][4];
#pragma unroll
    for (int i = 0; i < 4; i++)
#pragma unroll
        for (int j = 0; j < 4; j++) acc[i][j] = zero;

    for (int k0 = 0; k0 < DC; k0 += 64) {
#pragma unroll
        for (int c = 0; c < 4; c++) {
            int cid = c * 256 + tid;
            int row = cid >> 3, col8 = (cid & 7) * 8;
            unsigned short* lbase = &As[0][0] + (c * 256 + wave * 64) * 8;
            g2l16(&A[(m0 + row) * DC + k0 + col8], lbase);
            unsigned short* lbase2 = &Bs[0][0] + (c * 256 + wave * 64) * 8;
            g2l16(&Bt[(n0 + row) * DC + k0 + col8], lbase2);
        }
        __syncthreads();
#pragma unroll
        for (int kk = 0; kk < 64; kk += 32) {
            bf16x8 af[4], bfr[4];
#pragma unroll
            for (int mi = 0; mi < 4; mi++)
                af[mi] = *reinterpret_cast<const bf16x8*>(
                    &As[wm * 64 + mi * 16 + lane15][kk + quad * 8]);
#pragma unroll
            for (int ni = 0; ni < 4; ni++)
                bfr[ni] = *reinterpret_cast<const bf16x8*>(
                    &Bs[wn * 64 + ni * 16 + lane15][kk + quad * 8]);
#pragma unroll
            for (int mi = 0; mi < 4; mi++)
#pragma unroll
                for (int ni = 0; ni < 4; ni++)
                    acc[mi][ni] = __builtin_amdgcn_mfma_f32_16x16x32_bf16(
                        af[mi], bfr[ni], acc[mi][ni], 0, 0, 0);
        }
        __syncthreads();
    }
#pragma unroll
    for (int mi = 0; mi < 4; mi++)
#pragma unroll
        for (int ni = 0; ni < 4; ni++)
#pragma unroll
            for (int r = 0; r < 4; r++) {
                size_t row = m0 + wm * 64 + mi * 16 + quad * 4 + r;
                size_t col = n0 + wn * 64 + ni * 16 + lane15;
                C[row * DC + col] = f2bf(acc[mi][ni][r]);
            }
}

// ---- GEMM2: S = relu(H1_b @ V_b^T + bias); emit block-local top-k cands ---
// batch-major inputs; XCD-swizzled 1D grid (512 blocks)
__global__ __launch_bounds__(256) void gemm2_kernel(
    const unsigned short* __restrict__ A1,   // [32][512][1024] bf16 (H1)
    const unsigned short* __restrict__ V,    // [32][512][1024] bf16
    const int* __restrict__ m1t, const int* __restrict__ m2t,  // [32][512]
    const float* __restrict__ bptr,
    unsigned* __restrict__ cand,             // [32*16][CAP]
    unsigned* __restrict__ cnt) {            // [32*16]
    __shared__ unsigned short As[128][32];
    __shared__ unsigned short Bs[128][32];
    __shared__ unsigned lh[NBIN];
    __shared__ unsigned csum[256];
    __shared__ int m1s[128], m2s[128];
    __shared__ unsigned tsh, lcnt;
    int tid = threadIdx.x;
    int wave = tid >> 6, lane = tid & 63;
    int lane15 = lane & 15, quad = lane >> 4;
    int wm = wave >> 1, wn = wave & 1;
    // XCD swizzle: all 16 tiles of one batch share (linear id % 8) -> same XCD
    int L = blockIdx.x;
    int xcd = L & 7, tile = (L >> 3) & 15, chunk = L >> 7;
    int b = xcd + (chunk << 3);
    int bx = tile & 3, by = tile >> 2;
    int m0 = bx * 128, n0 = by * 128;
    int gblk = b * 16 + by * 4 + bx;
    const unsigned short* Ab = A1 + (size_t)b * L1C * DC;
    const unsigned short* Bb = V + (size_t)b * L2C * DC;

    for (int i = tid; i < NBIN; i += 256) lh[i] = 0;
    if (tid < 128) m1s[tid] = (m1t[b * L1C + m0 + tid] == 0);
    else           m2s[tid - 128] = (m2t[b * L2C + n0 + tid - 128] == 0);

    floatx4 zero = {0.f, 0.f, 0.f, 0.f};
    floatx4 acc[4][4];
#pragma unroll
    for (int i = 0; i < 4; i++)
#pragma unroll
        for (int j = 0; j < 4; j++) acc[i][j] = zero;

    for (int k0 = 0; k0 < DC; k0 += 32) {
#pragma unroll
        for (int c = 0; c < 2; c++) {
            int cid = c * 256 + tid;
            int row = cid >> 2, col8 = (cid & 3) * 8;
            unsigned short* lbase = &As[0][0] + (c * 256 + wave * 64) * 8;
            g2l16(&Ab[(size_t)(m0 + row) * DC + k0 + col8], lbase);
            unsigned short* lbase2 = &Bs[0][0] + (c * 256 + wave * 64) * 8;
            g2l16(&Bb[(size_t)(n0 + row) * DC + k0 + col8], lbase2);
        }
        __syncthreads();
        bf16x8 af[4], bfr[4];
#pragma unroll
        for (int mi = 0; mi < 4; mi++)
            af[mi] = *reinterpret_cast<const bf16x8*>(&As[wm * 64 + mi * 16 + lane15][quad * 8]);
#pragma unroll
        for (int ni = 0; ni < 4; ni++)
            bfr[ni] = *reinterpret_cast<const bf16x8*>(&Bs[wn * 64 + ni * 16 + lane15][quad * 8]);
#pragma unroll
        for (int mi = 0; mi < 4; mi++)
#pragma unroll
            for (int ni = 0; ni < 4; ni++)
                acc[mi][ni] = __builtin_amdgcn_mfma_f32_16x16x32_bf16(
                    af[mi], bfr[ni], acc[mi][ni], 0, 0, 0);
        __syncthreads();
    }

    float bias = bptr[0];
    // pass 1: local 4096-bin histogram of valid keys (zeros counted privately)
    unsigned zc = 0;
#pragma unroll
    for (int ni = 0; ni < 4; ni++) {
        int jl = wn * 64 + ni * 16 + lane15;
        int v2 = m2s[jl];
#pragma unroll
        for (int mi = 0; mi < 4; mi++)
#pragma unroll
            for (int r = 0; r < 4; r++) {
                int il = wm * 64 + mi * 16 + quad * 4 + r;
                float s = acc[mi][ni][r] + bias;
                if (v2 && m1s[il]) {
                    if (s > 0.f)
                        atomicAdd(&lh[(__float_as_uint(s) | 0x80000000u) >> 20], 1u);
                    else
                        zc++;
                }
            }
    }
    if (zc) atomicAdd(&lh[2048], zc);
    __syncthreads();
    unsigned s16 = 0;
#pragma unroll
    for (int i = 0; i < 16; i++) s16 += lh[tid * 16 + i];
    csum[tid] = s16;
    __syncthreads();
    if (tid == 0) {
        unsigned cum = 0, bin = 2048;
        int found = 0;
        for (int c = 255; c >= 128 && !found; --c) {
            unsigned cs = csum[c];
            if (cum + cs >= KTOP) {
                for (int bb = c * 16 + 15; bb >= c * 16; --bb) {
                    unsigned h = lh[bb];
                    if (cum + h >= KTOP) { bin = (unsigned)bb; found = 1; break; }
                    cum += h;
                }
            } else cum += cs;
        }
        tsh = bin << 20;
        lcnt = 0;
    }
    __syncthreads();
    // pass 2: emit keys >= block-local threshold
    unsigned T = tsh;
    unsigned base = (unsigned)gblk * CAP;
#pragma unroll
    for (int ni = 0; ni < 4; ni++) {
        int jl = wn * 64 + ni * 16 + lane15;
        int v2 = m2s[jl];
#pragma unroll
        for (int mi = 0; mi < 4; mi++)
#pragma unroll
            for (int r = 0; r < 4; r++) {
                int il = wm * 64 + mi * 16 + quad * 4 + r;
                float s = acc[mi][ni][r] + bias;
                s = s > 0.f ? s : 0.f;
                unsigned key = (v2 && m1s[il])
                                   ? (__float_as_uint(s) | 0x80000000u) : 0u;
                if (key >= T) {
                    unsigned p = atomicAdd(&lcnt, 1u);
                    if (p < CAP) cand[base + p] = key;
                }
            }
    }
    __syncthreads();
    if (tid == 0) cnt[gblk] = lcnt < CAP ? lcnt : CAP;
}

// ---- final: per batch, EXACT top-256 via 3-pass LDS radix select ----
__global__ __launch_bounds__(1024) void final_kernel(
    const unsigned* __restrict__ cand, const unsigned* __restrict__ cnt,
    float* __restrict__ out) {
    __shared__ unsigned buf[FBUF];     // 64 KB
    __shared__ unsigned h[NBIN];       // 16 KB
    __shared__ unsigned ss[256];       // suffix sums over chunks
    __shared__ unsigned scnt_s[16], off_s[16];
    __shared__ unsigned ntot_s, sel_c, sel_a, B_s, R_s, mcount;
    __shared__ int have_s;
    __shared__ unsigned srt[256];
    int b = blockIdx.x, tid = threadIdx.x;
    int wv = tid >> 6, ln = tid & 63;

    if (tid < 16) {
        unsigned c = cnt[b * 16 + tid];
        scnt_s[tid] = c < CAP ? c : CAP;
    }
    __syncthreads();
    if (tid == 0) {
        unsigned o = 0;
        for (int i = 0; i < 16; i++) { off_s[i] = o; o += scnt_s[i]; }
        ntot_s = o;
        have_s = 1;
    }
    __syncthreads();
    // wave-parallel staging: wave w copies segment w (all 16 in flight)
    {
        unsigned c = scnt_s[wv], o = off_s[wv];
        const unsigned* p = cand + (size_t)(b * 16 + wv) * CAP;
        for (unsigned i = ln; i < c; i += 64) buf[o + i] = p[i];
    }
    __syncthreads();
    unsigned n = ntot_s;

    unsigned Kr = KTOP;
    unsigned pfx = 0;
    unsigned kth = 0;
    for (int pass = 0; pass < 3; pass++) {
        int bins = (pass < 2) ? NBIN : 256;
        int shift = (pass == 0) ? 20 : (pass == 1) ? 8 : 0;
        int nch = bins >> 4;
        for (int i = tid; i < bins; i += 1024) h[i] = 0;
        __syncthreads();
        for (unsigned i = tid; i < n; i += 1024) {
            unsigned k = buf[i];
            bool ok = (pass == 0) ||
                      (pass == 1 && (k >> 20) == pfx) ||
                      (pass == 2 && (k >> 8) == pfx);
            if (ok) atomicAdd(&h[(k >> shift) & (bins - 1)], 1u);
        }
        __syncthreads();
        if (tid < nch) {
            unsigned s = 0;
#pragma unroll
            for (int i = 0; i < 16; i++) s += h[tid * 16 + i];
            ss[tid] = s;
        }
        __syncthreads();
        for (int off = 1; off < nch; off <<= 1) {
            unsigned v = 0;
            if (tid < nch && tid + (unsigned)off < (unsigned)nch) v = ss[tid + off];
            __syncthreads();
            if (tid < nch) ss[tid] += v;
            __syncthreads();
        }
        if (pass == 0) {
            if (tid == 0) have_s = (ss[0] >= KTOP);
            __syncthreads();
            if (!have_s) break;
        }
        if (tid < nch) {
            unsigned above = (tid + 1 < (unsigned)nch) ? ss[tid + 1] : 0u;
            if (above < Kr && ss[tid] >= Kr) { sel_c = tid; sel_a = above; }
        }
        __syncthreads();
        if (tid == 0) {
            unsigned cum = sel_a;
            for (int bb = (int)sel_c * 16 + 15; bb >= (int)sel_c * 16; --bb) {
                unsigned hb = h[bb];
                if (cum + hb >= Kr) { B_s = (unsigned)bb; R_s = Kr - cum; break; }
                cum += hb;
            }
        }
        __syncthreads();
        unsigned Bv = B_s;
        Kr = R_s;
        if (pass == 0) pfx = Bv;
        else if (pass == 1) pfx = (pfx << 12) | Bv;
        else kth = (pfx << 8) | Bv;
        __syncthreads();
    }

    if (tid == 0) mcount = 0;
    __syncthreads();
    int have = have_s;
    unsigned lim = have ? kth : 0u;
    for (unsigned i = tid; i < n; i += 1024) {
        unsigned k = buf[i];
        if (k > lim) {
            unsigned p = atomicAdd(&mcount, 1u);
            if (p < 256) srt[p] = k;
        }
    }
    __syncthreads();
    unsigned m = mcount;
    if (tid < 256 && tid >= (int)m) srt[tid] = have ? kth : 0u;
    for (int k2 = 2; k2 <= 256; k2 <<= 1) {
        for (int j2 = k2 >> 1; j2 > 0; j2 >>= 1) {
            __syncthreads();
            if (tid < 256) {
                int ixj = tid ^ j2;
                if (ixj > tid) {
                    unsigned a = srt[tid], c = srt[ixj];
                    bool up = (tid & k2) == 0;
                    if (up ? (a < c) : (a > c)) { srt[tid] = c; srt[ixj] = a; }
                }
            }
        }
    }
    __syncthreads();
    if (tid < 256) {
        unsigned nval = have ? KTOP : (m < KTOP ? m : KTOP);
        float v;
        if ((unsigned)tid < nval) v = decode_key(srt[tid]);
        else v = (nval > 0) ? decode_key(srt[nval - 1]) : -__builtin_inff();
        out[b * KTOP + tid] = v;
    }
}

// ---------------- launch ----------------
extern "C" void kernel_launch(void* const* d_in, const int* in_sizes, int n_in,
                              void* d_out, int out_size, void* d_ws, size_t ws_size,
                              hipStream_t stream) {
    const float* in1   = (const float*)d_in[0];   // [512,32,1024]
    const float* in2   = (const float*)d_in[1];   // [512,32,1024]
    const int*   mask1 = (const int*)d_in[2];     // [512,32]
    const int*   mask2 = (const int*)d_in[3];     // [512,32]
    const float* W     = (const float*)d_in[4];   // [1024,1024]
    const float* bias  = (const float*)d_in[5];   // [1]
    float* out = (float*)d_out;

    char* ws = (char*)d_ws;
    size_t off = 0;
    const size_t nElem = (size_t)L1C * BC * DC;       // 16777216
    unsigned short* A1 = (unsigned short*)(ws + off); off += nElem * 2;       // 32 MB
    unsigned short* A2 = (unsigned short*)(ws + off); off += nElem * 2;       // 32 MB
    unsigned short* Wb = (unsigned short*)(ws + off); off += (size_t)DC * DC * 2; // 2 MB
    unsigned short* V  = (unsigned short*)(ws + off); off += nElem * 2;       // 32 MB
    unsigned* cand = (unsigned*)(ws + off); off += (size_t)BC * 16 * CAP * 4; // 2 MB
    unsigned* cnt  = (unsigned*)(ws + off); off += (size_t)BC * 16 * 4;
    int* m1t = (int*)(ws + off); off += (size_t)BC * L1C * 4;
    int* m2t = (int*)(ws + off); off += (size_t)BC * L2C * 4;

    prep_kernel<<<2 * L1C * BC + DC + 64, 256, 0, stream>>>(
        in1, in2, W, mask1, mask2, A1, A2, Wb, m1t, m2t, cnt);
    gemm1_kernel<<<dim3(128, 8), 256, 0, stream>>>(A2, Wb, V);
    gemm2_kernel<<<512, 256, 0, stream>>>(A1, V, m1t, m2t, bias, cand, cnt);
    final_kernel<<<BC, 1024, 0, stream>>>(cand, cnt, out);
}

// Round 7
// 263.207 us; speedup vs baseline: 1.3645x; 1.0456x over previous
//
#include <hip/hip_runtime.h>

typedef __bf16 bf16_t;
typedef bf16_t bf16x8 __attribute__((ext_vector_type(8)));
typedef float floatx4 __attribute__((ext_vector_type(4)));

#define L1C 512
#define L2C 512
#define BC  32
#define DC  1024
#define KTOP 256
#define NBIN 4096           // 12-bit bins: sign+exp+3 mantissa bits
#define CAP  1024           // per-block candidate slots
#define FBUF 16384          // final-stage LDS candidate buffer

__device__ __forceinline__ unsigned short f2bf(float f) {
    unsigned u = __float_as_uint(f);
    u += 0x7FFFu + ((u >> 16) & 1u);   // RNE (data has no NaNs)
    return (unsigned short)(u >> 16);
}

// async global->LDS, 16B per lane; LDS dest = wave-uniform base + lane*16
__device__ __forceinline__ void g2l16(const unsigned short* g, unsigned short* l) {
    __builtin_amdgcn_global_load_lds((const unsigned int*)g, (unsigned int*)l,
                                     16, 0, 0);
}

__device__ __forceinline__ float decode_key(unsigned k) {
    return __uint_as_float(k & 0x7FFFFFFFu);
}

// ---- scan: per-batch valid-row index lists for both masks + cnt zero ----
// 32 blocks x 512 threads; mask layout [L,B]: elem (l,b) at l*32+b
__global__ __launch_bounds__(512) void scan_kernel(
    const int* __restrict__ mask1, const int* __restrict__ mask2,
    int* __restrict__ idx1, int* __restrict__ idx2,
    unsigned* __restrict__ nv1, unsigned* __restrict__ nv2,
    unsigned* __restrict__ cnt) {
    __shared__ unsigned sc[512];
    int b = blockIdx.x, t = threadIdx.x;
    for (int which = 0; which < 2; which++) {
        const int* m = which ? mask2 : mask1;
        int* idx = which ? idx2 : idx1;
        unsigned v = (m[t * BC + b] == 0) ? 1u : 0u;
        sc[t] = v;
        __syncthreads();
        for (int off = 1; off < 512; off <<= 1) {
            unsigned x = (t >= off) ? sc[t - off] : 0u;
            __syncthreads();
            sc[t] += x;
            __syncthreads();
        }
        if (v) idx[b * 512 + sc[t] - 1] = t;
        if (t == 511) { if (which) nv2[b] = sc[511]; else nv1[b] = sc[511]; }
        __syncthreads();
    }
    if (t < 16) cnt[b * 16 + t] = 0;
}

// ---- prep: compacting casts of in1/in2 (+zero pad to x128), W cast ----
// blocks [0,16384): A1c dest row (b,vi);  [16384,32768): A2c;  [32768,33792): W
__global__ __launch_bounds__(256) void prep_kernel(
    const float* __restrict__ in1, const float* __restrict__ in2,
    const float* __restrict__ W,
    const int* __restrict__ idx1, const int* __restrict__ idx2,
    const unsigned* __restrict__ nv1, const unsigned* __restrict__ nv2,
    unsigned short* __restrict__ A1c, unsigned short* __restrict__ A2c,
    unsigned short* __restrict__ Wb) {
    int r = blockIdx.x, t = threadIdx.x;
    const float* src;
    unsigned short* dst;
    if (r < 2 * 16384) {
        int which = r >> 14;            // 0: in1, 1: in2
        int rr = r & 16383;
        int b = rr >> 9, vi = rr & 511;
        unsigned nv = which ? nv2[b] : nv1[b];
        unsigned pad = (nv + 127u) & ~127u;
        if ((unsigned)vi >= pad) return;
        dst = (which ? A2c : A1c) + ((size_t)b * 512 + vi) * DC;
        if ((unsigned)vi < nv) {
            int l = (which ? idx2 : idx1)[b * 512 + vi];
            src = (which ? in2 : in1) + (size_t)(l * BC + b) * DC;
        } else {
            ushort4 z = {0, 0, 0, 0};
            reinterpret_cast<ushort4*>(dst)[t] = z;
            return;
        }
    } else {
        int r3 = r - 2 * 16384;
        src = W + (size_t)r3 * DC;
        dst = Wb + (size_t)r3 * DC;
    }
    float4 v = reinterpret_cast<const float4*>(src)[t];
    ushort4 o;
    o.x = f2bf(v.x); o.y = f2bf(v.y); o.z = f2bf(v.z); o.w = f2bf(v.w);
    reinterpret_cast<ushort4*>(dst)[t] = o;
}

// ---- GEMM1: V[b][j][d] = sum_e A2c[b][j][e] * Wb[d][e]  (BK=32) ----
// grid (128, 8): x -> (b, mt); early-exit tiles beyond pad2[b]
__global__ __launch_bounds__(256) void gemm1_kernel(
    const unsigned short* __restrict__ A,    // A2c [32][512][1024]
    const unsigned short* __restrict__ Bt,   // Wb  [1024][1024]
    unsigned short* __restrict__ C,          // V   [32][512][1024]
    const unsigned* __restrict__ nv2) {
    int bi = blockIdx.x >> 2, mt = blockIdx.x & 3;
    unsigned pad2 = (nv2[bi] + 127u) & ~127u;
    if ((unsigned)(mt * 128) >= pad2) return;
    __shared__ unsigned short As[128][32];
    __shared__ unsigned short Bs[128][32];
    int tid = threadIdx.x;
    int wave = tid >> 6, lane = tid & 63;
    int lane15 = lane & 15, quad = lane >> 4;
    int wm = wave >> 1, wn = wave & 1;
    size_t m0 = (size_t)bi * 512 + mt * 128;
    size_t n0 = (size_t)blockIdx.y * 128;

    floatx4 zero = {0.f, 0.f, 0.f, 0.f};
    floatx4 acc[4][4];
#pragma unroll
    for (int i = 0; i < 4; i++)
#pragma unroll
        for (int j = 0; j < 4; j++) acc[i][j] = zero;

    for (int k0 = 0; k0 < DC; k0 += 32) {
#pragma unroll
        for (int c = 0; c < 2; c++) {
            int cid = c * 256 + tid;
            int row = cid >> 2, col8 = (cid & 3) * 8;
            unsigned short* lbase = &As[0][0] + (c * 256 + wave * 64) * 8;
            g2l16(&A[(m0 + row) * DC + k0 + col8], lbase);
            unsigned short* lbase2 = &Bs[0][0] + (c * 256 + wave * 64) * 8;
            g2l16(&Bt[(n0 + row) * DC + k0 + col8], lbase2);
        }
        __syncthreads();
        bf16x8 af[4], bfr[4];
#pragma unroll
        for (int mi = 0; mi < 4; mi++)
            af[mi] = *reinterpret_cast<const bf16x8*>(&As[wm * 64 + mi * 16 + lane15][quad * 8]);
#pragma unroll
        for (int ni = 0; ni < 4; ni++)
            bfr[ni] = *reinterpret_cast<const bf16x8*>(&Bs[wn * 64 + ni * 16 + lane15][quad * 8]);
#pragma unroll
        for (int mi = 0; mi < 4; mi++)
#pragma unroll
            for (int ni = 0; ni < 4; ni++)
                acc[mi][ni] = __builtin_amdgcn_mfma_f32_16x16x32_bf16(
                    af[mi], bfr[ni], acc[mi][ni], 0, 0, 0);
        __syncthreads();
    }
#pragma unroll
    for (int mi = 0; mi < 4; mi++)
#pragma unroll
        for (int ni = 0; ni < 4; ni++)
#pragma unroll
            for (int r = 0; r < 4; r++) {
                size_t row = m0 + wm * 64 + mi * 16 + quad * 4 + r;
                size_t col = n0 + wn * 64 + ni * 16 + lane15;
                C[row * DC + col] = f2bf(acc[mi][ni][r]);
            }
}

// ---- GEMM2: S = relu(A1c_b @ V_b^T + bias) on valid x valid tiles ----
__global__ __launch_bounds__(256) void gemm2_kernel(
    const unsigned short* __restrict__ A1c,  // [32][512][1024]
    const unsigned short* __restrict__ V,    // [32][512][1024]
    const unsigned* __restrict__ nv1, const unsigned* __restrict__ nv2,
    const float* __restrict__ bptr,
    unsigned* __restrict__ cand,             // [32*16][CAP]
    unsigned* __restrict__ cnt) {            // [32*16]
    // XCD swizzle: all 16 tiles of one batch share (linear id % 8) -> same XCD
    int L = blockIdx.x;
    int xcd = L & 7, tile = (L >> 3) & 15, chunk = L >> 7;
    int b = xcd + (chunk << 3);
    int bx = tile & 3, by = tile >> 2;
    int m0 = bx * 128, n0 = by * 128;
    int gblk = b * 16 + by * 4 + bx;
    int tid = threadIdx.x;
    unsigned nv1v = nv1[b], nv2v = nv2[b];
    unsigned pad1 = (nv1v + 127u) & ~127u, pad2 = (nv2v + 127u) & ~127u;
    if ((unsigned)m0 >= pad1 || (unsigned)n0 >= pad2) {
        if (tid == 0) cnt[gblk] = 0;
        return;
    }
    __shared__ unsigned short As[128][32];
    __shared__ unsigned short Bs[128][32];
    __shared__ unsigned lh[NBIN];
    __shared__ unsigned csum[256];
    __shared__ unsigned tsh, lcnt, zeq;
    int wave = tid >> 6, lane = tid & 63;
    int lane15 = lane & 15, quad = lane >> 4;
    int wm = wave >> 1, wn = wave & 1;
    const unsigned short* Ab = A1c + (size_t)b * 512 * DC;
    const unsigned short* Bb = V + (size_t)b * 512 * DC;

    for (int i = tid; i < NBIN; i += 256) lh[i] = 0;

    floatx4 zero = {0.f, 0.f, 0.f, 0.f};
    floatx4 acc[4][4];
#pragma unroll
    for (int i = 0; i < 4; i++)
#pragma unroll
        for (int j = 0; j < 4; j++) acc[i][j] = zero;

    for (int k0 = 0; k0 < DC; k0 += 32) {
#pragma unroll
        for (int c = 0; c < 2; c++) {
            int cid = c * 256 + tid;
            int row = cid >> 2, col8 = (cid & 3) * 8;
            unsigned short* lbase = &As[0][0] + (c * 256 + wave * 64) * 8;
            g2l16(&Ab[(size_t)(m0 + row) * DC + k0 + col8], lbase);
            unsigned short* lbase2 = &Bs[0][0] + (c * 256 + wave * 64) * 8;
            g2l16(&Bb[(size_t)(n0 + row) * DC + k0 + col8], lbase2);
        }
        __syncthreads();
        bf16x8 af[4], bfr[4];
#pragma unroll
        for (int mi = 0; mi < 4; mi++)
            af[mi] = *reinterpret_cast<const bf16x8*>(&As[wm * 64 + mi * 16 + lane15][quad * 8]);
#pragma unroll
        for (int ni = 0; ni < 4; ni++)
            bfr[ni] = *reinterpret_cast<const bf16x8*>(&Bs[wn * 64 + ni * 16 + lane15][quad * 8]);
#pragma unroll
        for (int mi = 0; mi < 4; mi++)
#pragma unroll
            for (int ni = 0; ni < 4; ni++)
                acc[mi][ni] = __builtin_amdgcn_mfma_f32_16x16x32_bf16(
                    af[mi], bfr[ni], acc[mi][ni], 0, 0, 0);
        __syncthreads();
    }

    float bias = bptr[0];
    // pass 1: 4096-bin histogram of valid keys (zero scores counted privately)
    unsigned zc = 0;
#pragma unroll
    for (int ni = 0; ni < 4; ni++) {
        int jl = n0 + wn * 64 + ni * 16 + lane15;
        int v2 = (unsigned)jl < nv2v;
#pragma unroll
        for (int mi = 0; mi < 4; mi++)
#pragma unroll
            for (int r = 0; r < 4; r++) {
                int il = m0 + wm * 64 + mi * 16 + quad * 4 + r;
                float s = acc[mi][ni][r] + bias;
                if (v2 && (unsigned)il < nv1v) {
                    if (s > 0.f)
                        atomicAdd(&lh[(__float_as_uint(s) | 0x80000000u) >> 20], 1u);
                    else
                        zc++;
                }
            }
    }
    if (zc) atomicAdd(&lh[2048], zc);
    __syncthreads();
    unsigned s16 = 0;
#pragma unroll
    for (int i = 0; i < 16; i++) s16 += lh[tid * 16 + i];
    csum[tid] = s16;
    __syncthreads();
    if (tid == 0) {
        unsigned cum = 0, bin = 2048;
        int found = 0;
        for (int c = 255; c >= 128 && !found; --c) {
            unsigned cs = csum[c];
            if (cum + cs >= KTOP) {
                for (int bb = c * 16 + 15; bb >= c * 16; --bb) {
                    unsigned h = lh[bb];
                    if (cum + h >= KTOP) { bin = (unsigned)bb; found = 1; break; }
                    cum += h;
                }
            } else cum += cs;
        }
        tsh = bin << 20;
        lcnt = 0;
        zeq = 0;
    }
    __syncthreads();
    // pass 2: emit keys >= threshold; exact-T ties gated to <= KTOP
    unsigned T = tsh;
    unsigned base = (unsigned)gblk * CAP;
#pragma unroll
    for (int ni = 0; ni < 4; ni++) {
        int jl = n0 + wn * 64 + ni * 16 + lane15;
        int v2 = (unsigned)jl < nv2v;
#pragma unroll
        for (int mi = 0; mi < 4; mi++)
#pragma unroll
            for (int r = 0; r < 4; r++) {
                int il = m0 + wm * 64 + mi * 16 + quad * 4 + r;
                float s = acc[mi][ni][r] + bias;
                s = s > 0.f ? s : 0.f;
                unsigned key = (v2 && (unsigned)il < nv1v)
                                   ? (__float_as_uint(s) | 0x80000000u) : 0u;
                if (key > T) {
                    unsigned p = atomicAdd(&lcnt, 1u);
                    if (p < CAP) cand[base + p] = key;
                } else if (key == T) {
                    unsigned z = atomicAdd(&zeq, 1u);
                    if (z < KTOP) {
                        unsigned p = atomicAdd(&lcnt, 1u);
                        if (p < CAP) cand[base + p] = key;
                    }
                }
            }
    }
    __syncthreads();
    if (tid == 0) cnt[gblk] = lcnt < CAP ? lcnt : CAP;
}

// ---- final: per batch, EXACT top-256 via 3-pass LDS radix select ----
__global__ __launch_bounds__(1024) void final_kernel(
    const unsigned* __restrict__ cand, const unsigned* __restrict__ cnt,
    float* __restrict__ out) {
    __shared__ unsigned buf[FBUF];     // 64 KB
    __shared__ unsigned h[NBIN];       // 16 KB
    __shared__ unsigned ss[256];
    __shared__ unsigned scnt_s[16], off_s[16];
    __shared__ unsigned ntot_s, sel_c, sel_a, B_s, R_s, mcount;
    __shared__ int have_s;
    __shared__ unsigned srt[256];
    int b = blockIdx.x, tid = threadIdx.x;
    int wv = tid >> 6, ln = tid & 63;

    if (tid < 16) {
        unsigned c = cnt[b * 16 + tid];
        scnt_s[tid] = c < CAP ? c : CAP;
    }
    __syncthreads();
    if (tid == 0) {
        unsigned o = 0;
        for (int i = 0; i < 16; i++) { off_s[i] = o; o += scnt_s[i]; }
        ntot_s = o;
        have_s = 1;
    }
    __syncthreads();
    {   // wave-parallel staging
        unsigned c = scnt_s[wv], o = off_s[wv];
        const unsigned* p = cand + (size_t)(b * 16 + wv) * CAP;
        for (unsigned i = ln; i < c; i += 64) buf[o + i] = p[i];
    }
    __syncthreads();
    unsigned n = ntot_s;

    unsigned Kr = KTOP;
    unsigned pfx = 0;
    unsigned kth = 0;
    for (int pass = 0; pass < 3; pass++) {
        int bins = (pass < 2) ? NBIN : 256;
        int shift = (pass == 0) ? 20 : (pass == 1) ? 8 : 0;
        int nch = bins >> 4;
        for (int i = tid; i < bins; i += 1024) h[i] = 0;
        __syncthreads();
        for (unsigned i = tid; i < n; i += 1024) {
            unsigned k = buf[i];
            bool ok = (pass == 0) ||
                      (pass == 1 && (k >> 20) == pfx) ||
                      (pass == 2 && (k >> 8) == pfx);
            if (ok) atomicAdd(&h[(k >> shift) & (bins - 1)], 1u);
        }
        __syncthreads();
        if (tid < nch) {
            unsigned s = 0;
#pragma unroll
            for (int i = 0; i < 16; i++) s += h[tid * 16 + i];
            ss[tid] = s;
        }
        __syncthreads();
        for (int off = 1; off < nch; off <<= 1) {
            unsigned v = 0;
            if (tid < nch && tid + (unsigned)off < (unsigned)nch) v = ss[tid + off];
            __syncthreads();
            if (tid < nch) ss[tid] += v;
            __syncthreads();
        }
        if (pass == 0) {
            if (tid == 0) have_s = (ss[0] >= KTOP);
            __syncthreads();
            if (!have_s) break;
        }
        if (tid < nch) {
            unsigned above = (tid + 1 < (unsigned)nch) ? ss[tid + 1] : 0u;
            if (above < Kr && ss[tid] >= Kr) { sel_c = tid; sel_a = above; }
        }
        __syncthreads();
        if (tid == 0) {
            unsigned cum = sel_a;
            for (int bb = (int)sel_c * 16 + 15; bb >= (int)sel_c * 16; --bb) {
                unsigned hb = h[bb];
                if (cum + hb >= Kr) { B_s = (unsigned)bb; R_s = Kr - cum; break; }
                cum += hb;
            }
        }
        __syncthreads();
        unsigned Bv = B_s;
        Kr = R_s;
        if (pass == 0) pfx = Bv;
        else if (pass == 1) pfx = (pfx << 12) | Bv;
        else kth = (pfx << 8) | Bv;
        __syncthreads();
    }

    if (tid == 0) mcount = 0;
    __syncthreads();
    int have = have_s;
    unsigned lim = have ? kth : 0u;
    for (unsigned i = tid; i < n; i += 1024) {
        unsigned k = buf[i];
        if (k > lim) {
            unsigned p = atomicAdd(&mcount, 1u);
            if (p < 256) srt[p] = k;
        }
    }
    __syncthreads();
    unsigned m = mcount;
    if (tid < 256 && tid >= (int)m) srt[tid] = have ? kth : 0u;
    for (int k2 = 2; k2 <= 256; k2 <<= 1) {
        for (int j2 = k2 >> 1; j2 > 0; j2 >>= 1) {
            __syncthreads();
            if (tid < 256) {
                int ixj = tid ^ j2;
                if (ixj > tid) {
                    unsigned a = srt[tid], c = srt[ixj];
                    bool up = (tid & k2) == 0;
                    if (up ? (a < c) : (a > c)) { srt[tid] = c; srt[ixj] = a; }
                }
            }
        }
    }
    __syncthreads();
    if (tid < 256) {
        unsigned nval = have ? KTOP : (m < KTOP ? m : KTOP);
        float v;
        if ((unsigned)tid < nval) v = decode_key(srt[tid]);
        else v = (nval > 0) ? decode_key(srt[nval - 1]) : -__builtin_inff();
        out[b * KTOP + tid] = v;
    }
}

// ---------------- launch ----------------
extern "C" void kernel_launch(void* const* d_in, const int* in_sizes, int n_in,
                              void* d_out, int out_size, void* d_ws, size_t ws_size,
                              hipStream_t stream) {
    const float* in1   = (const float*)d_in[0];   // [512,32,1024]
    const float* in2   = (const float*)d_in[1];   // [512,32,1024]
    const int*   mask1 = (const int*)d_in[2];     // [512,32]
    const int*   mask2 = (const int*)d_in[3];     // [512,32]
    const float* W     = (const float*)d_in[4];   // [1024,1024]
    const float* bias  = (const float*)d_in[5];   // [1]
    float* out = (float*)d_out;

    char* ws = (char*)d_ws;
    size_t off = 0;
    const size_t nElem = (size_t)512 * BC * DC;
    unsigned short* A1c = (unsigned short*)(ws + off); off += nElem * 2;      // 32 MB
    unsigned short* A2c = (unsigned short*)(ws + off); off += nElem * 2;      // 32 MB
    unsigned short* Wb  = (unsigned short*)(ws + off); off += (size_t)DC * DC * 2; // 2 MB
    unsigned short* V   = (unsigned short*)(ws + off); off += nElem * 2;      // 32 MB
    unsigned* cand = (unsigned*)(ws + off); off += (size_t)BC * 16 * CAP * 4; // 2 MB
    unsigned* cnt  = (unsigned*)(ws + off); off += (size_t)BC * 16 * 4;
    int* idx1 = (int*)(ws + off); off += (size_t)BC * 512 * 4;
    int* idx2 = (int*)(ws + off); off += (size_t)BC * 512 * 4;
    unsigned* nv1 = (unsigned*)(ws + off); off += BC * 4;
    unsigned* nv2 = (unsigned*)(ws + off); off += BC * 4;

    scan_kernel<<<BC, 512, 0, stream>>>(mask1, mask2, idx1, idx2, nv1, nv2, cnt);
    prep_kernel<<<2 * 16384 + 1024, 256, 0, stream>>>(
        in1, in2, W, idx1, idx2, nv1, nv2, A1c, A2c, Wb);
    gemm1_kernel<<<dim3(128, 8), 256, 0, stream>>>(A2c, Wb, V, nv2);
    gemm2_kernel<<<512, 256, 0, stream>>>(A1c, V, nv1, nv2, bias, cand, cnt);
    final_kernel<<<BC, 1024, 0, stream>>>(cand, cnt, out);
}

// Round 8
// 262.090 us; speedup vs baseline: 1.3703x; 1.0043x over previous
//
#include <hip/hip_runtime.h>

typedef __bf16 bf16_t;
typedef bf16_t bf16x8 __attribute__((ext_vector_type(8)));
typedef float floatx4 __attribute__((ext_vector_type(4)));

#define L1C 512
#define L2C 512
#define BC  32
#define DC  1024
#define KTOP 256
#define NBIN 4096           // 12-bit bins: sign+exp+3 mantissa bits
#define CAP  512            // per-block candidate slots (64x64 tile)
#define NT   64             // tiles per batch in gemm2 (8x8)
#define FBUF 16384          // final-stage LDS candidate buffer

__device__ __forceinline__ unsigned short f2bf(float f) {
    unsigned u = __float_as_uint(f);
    u += 0x7FFFu + ((u >> 16) & 1u);   // RNE (data has no NaNs)
    return (unsigned short)(u >> 16);
}

// async global->LDS, 16B per lane; LDS dest = wave-uniform base + lane*16
__device__ __forceinline__ void g2l16(const unsigned short* g, unsigned short* l) {
    __builtin_amdgcn_global_load_lds((const unsigned int*)g, (unsigned int*)l,
                                     16, 0, 0);
}

__device__ __forceinline__ float decode_key(unsigned k) {
    return __uint_as_float(k & 0x7FFFFFFFu);
}

// ---- scan: per-batch valid-row index lists for both masks + cnt zero ----
__global__ __launch_bounds__(512) void scan_kernel(
    const int* __restrict__ mask1, const int* __restrict__ mask2,
    int* __restrict__ idx1, int* __restrict__ idx2,
    unsigned* __restrict__ nv1, unsigned* __restrict__ nv2,
    unsigned* __restrict__ cnt) {
    __shared__ unsigned sc[512];
    int b = blockIdx.x, t = threadIdx.x;
    for (int which = 0; which < 2; which++) {
        const int* m = which ? mask2 : mask1;
        int* idx = which ? idx2 : idx1;
        unsigned v = (m[t * BC + b] == 0) ? 1u : 0u;
        sc[t] = v;
        __syncthreads();
        for (int off = 1; off < 512; off <<= 1) {
            unsigned x = (t >= off) ? sc[t - off] : 0u;
            __syncthreads();
            sc[t] += x;
            __syncthreads();
        }
        if (v) idx[b * 512 + sc[t] - 1] = t;
        if (t == 511) { if (which) nv2[b] = sc[511]; else nv1[b] = sc[511]; }
        __syncthreads();
    }
    if (t < NT) cnt[b * NT + t] = 0;
}

// ---- prep: compacting casts of in1/in2 (+zero pad to x64), W cast ----
__global__ __launch_bounds__(256) void prep_kernel(
    const float* __restrict__ in1, const float* __restrict__ in2,
    const float* __restrict__ W,
    const int* __restrict__ idx1, const int* __restrict__ idx2,
    const unsigned* __restrict__ nv1, const unsigned* __restrict__ nv2,
    unsigned short* __restrict__ A1c, unsigned short* __restrict__ A2c,
    unsigned short* __restrict__ Wb) {
    int r = blockIdx.x, t = threadIdx.x;
    const float* src;
    unsigned short* dst;
    if (r < 2 * 16384) {
        int which = r >> 14;            // 0: in1, 1: in2
        int rr = r & 16383;
        int b = rr >> 9, vi = rr & 511;
        unsigned nv = which ? nv2[b] : nv1[b];
        unsigned pad = (nv + 63u) & ~63u;
        if ((unsigned)vi >= pad) return;
        dst = (which ? A2c : A1c) + ((size_t)b * 512 + vi) * DC;
        if ((unsigned)vi < nv) {
            int l = (which ? idx2 : idx1)[b * 512 + vi];
            src = (which ? in2 : in1) + (size_t)(l * BC + b) * DC;
        } else {
            ushort4 z = {0, 0, 0, 0};
            reinterpret_cast<ushort4*>(dst)[t] = z;
            return;
        }
    } else {
        int r3 = r - 2 * 16384;
        src = W + (size_t)r3 * DC;
        dst = Wb + (size_t)r3 * DC;
    }
    float4 v = reinterpret_cast<const float4*>(src)[t];
    ushort4 o;
    o.x = f2bf(v.x); o.y = f2bf(v.y); o.z = f2bf(v.z); o.w = f2bf(v.w);
    reinterpret_cast<ushort4*>(dst)[t] = o;
}

// ---- GEMM1: V[b][j][d] = sum_e A2c[b][j][e] * Wb[d][e]  (64x128 tile) ----
// grid (256, 8): x -> (bi, mt 0..7 of 64 rows); early-exit beyond pad2
__global__ __launch_bounds__(256) void gemm1_kernel(
    const unsigned short* __restrict__ A,    // A2c [32][512][1024]
    const unsigned short* __restrict__ Bt,   // Wb  [1024][1024]
    unsigned short* __restrict__ C,          // V   [32][512][1024]
    const unsigned* __restrict__ nv2) {
    int bi = blockIdx.x >> 3, mt = blockIdx.x & 7;
    unsigned pad2 = (nv2[bi] + 63u) & ~63u;
    if ((unsigned)(mt * 64) >= pad2) return;
    __shared__ unsigned short As[64][32];
    __shared__ unsigned short Bs[128][32];
    int tid = threadIdx.x;
    int wave = tid >> 6, lane = tid & 63;
    int lane15 = lane & 15, quad = lane >> 4;
    size_t m0 = (size_t)bi * 512 + mt * 64;
    size_t n0 = (size_t)blockIdx.y * 128;

    floatx4 zero = {0.f, 0.f, 0.f, 0.f};
    floatx4 acc[4][2];
#pragma unroll
    for (int i = 0; i < 4; i++)
#pragma unroll
        for (int j = 0; j < 2; j++) acc[i][j] = zero;

    for (int k0 = 0; k0 < DC; k0 += 32) {
        {   // As: 64 rows x 32 cols = 256 chunks
            int row = tid >> 2, col8 = (tid & 3) * 8;
            g2l16(&A[(m0 + row) * DC + k0 + col8],
                  &As[0][0] + (wave * 64) * 8);
        }
#pragma unroll
        for (int c = 0; c < 2; c++) {  // Bs: 128 rows = 512 chunks
            int cid2 = c * 256 + tid;
            int row = cid2 >> 2, col8 = (cid2 & 3) * 8;
            g2l16(&Bt[(n0 + row) * DC + k0 + col8],
                  &Bs[0][0] + (c * 256 + wave * 64) * 8);
        }
        __syncthreads();
        bf16x8 af[4], bfr[2];
#pragma unroll
        for (int mi = 0; mi < 4; mi++)
            af[mi] = *reinterpret_cast<const bf16x8*>(&As[mi * 16 + lane15][quad * 8]);
#pragma unroll
        for (int ni = 0; ni < 2; ni++)
            bfr[ni] = *reinterpret_cast<const bf16x8*>(
                &Bs[wave * 32 + ni * 16 + lane15][quad * 8]);
#pragma unroll
        for (int mi = 0; mi < 4; mi++)
#pragma unroll
            for (int ni = 0; ni < 2; ni++)
                acc[mi][ni] = __builtin_amdgcn_mfma_f32_16x16x32_bf16(
                    af[mi], bfr[ni], acc[mi][ni], 0, 0, 0);
        __syncthreads();
    }
#pragma unroll
    for (int mi = 0; mi < 4; mi++)
#pragma unroll
        for (int ni = 0; ni < 2; ni++)
#pragma unroll
            for (int r = 0; r < 4; r++) {
                size_t row = m0 + mi * 16 + quad * 4 + r;
                size_t col = n0 + wave * 32 + ni * 16 + lane15;
                C[row * DC + col] = f2bf(acc[mi][ni][r]);
            }
}

// ---- GEMM2: 64x64 tiles; S = relu(A1c_b @ V_b^T + bias); top-k cands ----
__global__ __launch_bounds__(256) void gemm2_kernel(
    const unsigned short* __restrict__ A1c,  // [32][512][1024]
    const unsigned short* __restrict__ V,    // [32][512][1024]
    const unsigned* __restrict__ nv1, const unsigned* __restrict__ nv2,
    const float* __restrict__ bptr,
    unsigned* __restrict__ cand,             // [32*NT][CAP]
    unsigned* __restrict__ cnt) {            // [32*NT]
    // XCD swizzle: same xcd -> same batch
    int L = blockIdx.x;
    int xcd = L & 7, tile = (L >> 3) & 63, chunk = L >> 9;
    int b = xcd + (chunk << 3);
    int tx = tile & 7, ty = tile >> 3;
    int m0 = ty * 64, n0 = tx * 64;
    int gblk = b * NT + tile;
    int tid = threadIdx.x;
    unsigned nv1v = nv1[b], nv2v = nv2[b];
    unsigned pad1 = (nv1v + 63u) & ~63u, pad2 = (nv2v + 63u) & ~63u;
    if ((unsigned)m0 >= pad1 || (unsigned)n0 >= pad2) {
        if (tid == 0) cnt[gblk] = 0;
        return;
    }
    __shared__ unsigned short As[64][32];
    __shared__ unsigned short Bs[64][32];
    __shared__ unsigned lh[NBIN];
    __shared__ unsigned csum[256];
    __shared__ unsigned sel_c, sel_a, tsh, lcnt, zeq;
    int wave = tid >> 6, lane = tid & 63;
    int lane15 = lane & 15, quad = lane >> 4;
    const unsigned short* Ab = A1c + (size_t)b * 512 * DC;
    const unsigned short* Bb = V + (size_t)b * 512 * DC;

    for (int i = tid; i < NBIN; i += 256) lh[i] = 0;
    if (tid == 0) { sel_c = 0xFFFFFFFFu; lcnt = 0; zeq = 0; }

    floatx4 zero = {0.f, 0.f, 0.f, 0.f};
    floatx4 acc[4];
#pragma unroll
    for (int i = 0; i < 4; i++) acc[i] = zero;

    for (int k0 = 0; k0 < DC; k0 += 32) {
        int row = tid >> 2, col8 = (tid & 3) * 8;
        g2l16(&Ab[(size_t)(m0 + row) * DC + k0 + col8],
              &As[0][0] + (wave * 64) * 8);
        g2l16(&Bb[(size_t)(n0 + row) * DC + k0 + col8],
              &Bs[0][0] + (wave * 64) * 8);
        __syncthreads();
        bf16x8 af, bfr[4];
        af = *reinterpret_cast<const bf16x8*>(&As[wave * 16 + lane15][quad * 8]);
#pragma unroll
        for (int ni = 0; ni < 4; ni++)
            bfr[ni] = *reinterpret_cast<const bf16x8*>(&Bs[ni * 16 + lane15][quad * 8]);
#pragma unroll
        for (int ni = 0; ni < 4; ni++)
            acc[ni] = __builtin_amdgcn_mfma_f32_16x16x32_bf16(
                af, bfr[ni], acc[ni], 0, 0, 0);
        __syncthreads();
    }

    float bias = bptr[0];
    // pass 1: 4096-bin histogram (zero scores privatized)
    unsigned zc = 0;
#pragma unroll
    for (int ni = 0; ni < 4; ni++) {
        int jl = n0 + ni * 16 + lane15;
        int v2 = (unsigned)jl < nv2v;
#pragma unroll
        for (int r = 0; r < 4; r++) {
            int il = m0 + wave * 16 + quad * 4 + r;
            float s = acc[ni][r] + bias;
            if (v2 && (unsigned)il < nv1v) {
                if (s > 0.f)
                    atomicAdd(&lh[(__float_as_uint(s) | 0x80000000u) >> 20], 1u);
                else
                    zc++;
            }
        }
    }
    if (zc) atomicAdd(&lh[2048], zc);
    __syncthreads();
    unsigned s16 = 0;
#pragma unroll
    for (int i = 0; i < 16; i++) s16 += lh[tid * 16 + i];
    csum[tid] = s16;
    __syncthreads();
    // parallel suffix scan over 256 chunks
    for (int off = 1; off < 256; off <<= 1) {
        unsigned v = (tid + off < 256) ? csum[tid + off] : 0u;
        __syncthreads();
        csum[tid] += v;
        __syncthreads();
    }
    {   // locate chunk holding the 256th (valid chunks are >=128)
        unsigned above = (tid < 255) ? csum[tid + 1] : 0u;
        if (tid >= 128 && csum[tid] >= KTOP && above < KTOP) {
            sel_c = (unsigned)tid; sel_a = above;
        }
    }
    __syncthreads();
    if (tid == 0) {
        if (sel_c == 0xFFFFFFFFu) {
            tsh = 2048u << 20;          // fewer than k valid: take all
        } else {
            unsigned cum = sel_a, bin = 2048;
            for (int bb = (int)sel_c * 16 + 15; bb >= (int)sel_c * 16; --bb) {
                unsigned hb = lh[bb];
                if (cum + hb >= KTOP) { bin = (unsigned)bb; break; }
                cum += hb;
            }
            tsh = bin << 20;
        }
    }
    __syncthreads();
    // pass 2: emit; exact-T ties gated to <= KTOP
    unsigned T = tsh;
    unsigned base = (unsigned)gblk * CAP;
#pragma unroll
    for (int ni = 0; ni < 4; ni++) {
        int jl = n0 + ni * 16 + lane15;
        int v2 = (unsigned)jl < nv2v;
#pragma unroll
        for (int r = 0; r < 4; r++) {
            int il = m0 + wave * 16 + quad * 4 + r;
            float s = acc[ni][r] + bias;
            s = s > 0.f ? s : 0.f;
            unsigned key = (v2 && (unsigned)il < nv1v)
                               ? (__float_as_uint(s) | 0x80000000u) : 0u;
            if (key > T) {
                unsigned p = atomicAdd(&lcnt, 1u);
                if (p < CAP) cand[base + p] = key;
            } else if (key == T) {
                unsigned z = atomicAdd(&zeq, 1u);
                if (z < KTOP) {
                    unsigned p = atomicAdd(&lcnt, 1u);
                    if (p < CAP) cand[base + p] = key;
                }
            }
        }
    }
    __syncthreads();
    if (tid == 0) cnt[gblk] = lcnt < CAP ? lcnt : CAP;
}

// ---- final: per batch, EXACT top-256 via 3-pass LDS radix select ----
__global__ __launch_bounds__(1024) void final_kernel(
    const unsigned* __restrict__ cand, const unsigned* __restrict__ cnt,
    float* __restrict__ out) {
    __shared__ unsigned buf[FBUF];     // 64 KB
    __shared__ unsigned h[NBIN];       // 16 KB
    __shared__ unsigned ss[256];
    __shared__ unsigned scnt_s[NT], off_s[NT];
    __shared__ unsigned ntot_s, sel_c, sel_a, B_s, R_s, mcount;
    __shared__ int have_s;
    __shared__ unsigned srt[256];
    int b = blockIdx.x, tid = threadIdx.x;
    int wv = tid >> 6, ln = tid & 63;

    if (tid < NT) {
        unsigned c = cnt[b * NT + tid];
        scnt_s[tid] = c < CAP ? c : CAP;
    }
    __syncthreads();
    if (tid == 0) {
        unsigned o = 0;
        for (int i = 0; i < NT; i++) {
            unsigned c = scnt_s[i];
            if (o + c > FBUF) c = (o < FBUF) ? FBUF - o : 0;
            scnt_s[i] = c;
            off_s[i] = o;
            o += c;
        }
        ntot_s = o;
        have_s = 1;
    }
    __syncthreads();
    // wave-parallel staging: wave wv handles segments wv, wv+16, ...
    for (int s = wv; s < NT; s += 16) {
        unsigned c = scnt_s[s], o = off_s[s];
        const unsigned* p = cand + (size_t)(b * NT + s) * CAP;
        for (unsigned i = ln; i < c; i += 64) buf[o + i] = p[i];
    }
    __syncthreads();
    unsigned n = ntot_s;

    unsigned Kr = KTOP;
    unsigned pfx = 0;
    unsigned kth = 0;
    for (int pass = 0; pass < 3; pass++) {
        int bins = (pass < 2) ? NBIN : 256;
        int shift = (pass == 0) ? 20 : (pass == 1) ? 8 : 0;
        int nch = bins >> 4;
        for (int i = tid; i < bins; i += 1024) h[i] = 0;
        __syncthreads();
        for (unsigned i = tid; i < n; i += 1024) {
            unsigned k = buf[i];
            bool ok = (pass == 0) ||
                      (pass == 1 && (k >> 20) == pfx) ||
                      (pass == 2 && (k >> 8) == pfx);
            if (ok) atomicAdd(&h[(k >> shift) & (bins - 1)], 1u);
        }
        __syncthreads();
        if (tid < nch) {
            unsigned s = 0;
#pragma unroll
            for (int i = 0; i < 16; i++) s += h[tid * 16 + i];
            ss[tid] = s;
        }
        __syncthreads();
        for (int off = 1; off < nch; off <<= 1) {
            unsigned v = 0;
            if (tid < nch && tid + (unsigned)off < (unsigned)nch) v = ss[tid + off];
            __syncthreads();
            if (tid < nch) ss[tid] += v;
            __syncthreads();
        }
        if (pass == 0) {
            if (tid == 0) have_s = (ss[0] >= KTOP);
            __syncthreads();
            if (!have_s) break;
        }
        if (tid < nch) {
            unsigned above = (tid + 1 < (unsigned)nch) ? ss[tid + 1] : 0u;
            if (above < Kr && ss[tid] >= Kr) { sel_c = tid; sel_a = above; }
        }
        __syncthreads();
        if (tid == 0) {
            unsigned cum = sel_a;
            for (int bb = (int)sel_c * 16 + 15; bb >= (int)sel_c * 16; --bb) {
                unsigned hb = h[bb];
                if (cum + hb >= Kr) { B_s = (unsigned)bb; R_s = Kr - cum; break; }
                cum += hb;
            }
        }
        __syncthreads();
        unsigned Bv = B_s;
        Kr = R_s;
        if (pass == 0) pfx = Bv;
        else if (pass == 1) pfx = (pfx << 12) | Bv;
        else kth = (pfx << 8) | Bv;
        __syncthreads();
    }

    if (tid == 0) mcount = 0;
    __syncthreads();
    int have = have_s;
    unsigned lim = have ? kth : 0u;
    for (unsigned i = tid; i < n; i += 1024) {
        unsigned k = buf[i];
        if (k > lim) {
            unsigned p = atomicAdd(&mcount, 1u);
            if (p < 256) srt[p] = k;
        }
    }
    __syncthreads();
    unsigned m = mcount;
    if (tid < 256 && tid >= (int)m) srt[tid] = have ? kth : 0u;
    for (int k2 = 2; k2 <= 256; k2 <<= 1) {
        for (int j2 = k2 >> 1; j2 > 0; j2 >>= 1) {
            __syncthreads();
            if (tid < 256) {
                int ixj = tid ^ j2;
                if (ixj > tid) {
                    unsigned a = srt[tid], c = srt[ixj];
                    bool up = (tid & k2) == 0;
                    if (up ? (a < c) : (a > c)) { srt[tid] = c; srt[ixj] = a; }
                }
            }
        }
    }
    __syncthreads();
    if (tid < 256) {
        unsigned nval = have ? KTOP : (m < KTOP ? m : KTOP);
        float v;
        if ((unsigned)tid < nval) v = decode_key(srt[tid]);
        else v = (nval > 0) ? decode_key(srt[nval - 1]) : -__builtin_inff();
        out[b * KTOP + tid] = v;
    }
}

// ---------------- launch ----------------
extern "C" void kernel_launch(void* const* d_in, const int* in_sizes, int n_in,
                              void* d_out, int out_size, void* d_ws, size_t ws_size,
                              hipStream_t stream) {
    const float* in1   = (const float*)d_in[0];   // [512,32,1024]
    const float* in2   = (const float*)d_in[1];   // [512,32,1024]
    const int*   mask1 = (const int*)d_in[2];     // [512,32]
    const int*   mask2 = (const int*)d_in[3];     // [512,32]
    const float* W     = (const float*)d_in[4];   // [1024,1024]
    const float* bias  = (const float*)d_in[5];   // [1]
    float* out = (float*)d_out;

    char* ws = (char*)d_ws;
    size_t off = 0;
    const size_t nElem = (size_t)512 * BC * DC;
    unsigned short* A1c = (unsigned short*)(ws + off); off += nElem * 2;      // 32 MB
    unsigned short* A2c = (unsigned short*)(ws + off); off += nElem * 2;      // 32 MB
    unsigned short* Wb  = (unsigned short*)(ws + off); off += (size_t)DC * DC * 2; // 2 MB
    unsigned short* V   = (unsigned short*)(ws + off); off += nElem * 2;      // 32 MB
    unsigned* cand = (unsigned*)(ws + off); off += (size_t)BC * NT * CAP * 4; // 4 MB
    unsigned* cnt  = (unsigned*)(ws + off); off += (size_t)BC * NT * 4;
    int* idx1 = (int*)(ws + off); off += (size_t)BC * 512 * 4;
    int* idx2 = (int*)(ws + off); off += (size_t)BC * 512 * 4;
    unsigned* nv1 = (unsigned*)(ws + off); off += BC * 4;
    unsigned* nv2 = (unsigned*)(ws + off); off += BC * 4;

    scan_kernel<<<BC, 512, 0, stream>>>(mask1, mask2, idx1, idx2, nv1, nv2, cnt);
    prep_kernel<<<2 * 16384 + 1024, 256, 0, stream>>>(
        in1, in2, W, idx1, idx2, nv1, nv2, A1c, A2c, Wb);
    gemm1_kernel<<<dim3(256, 8), 256, 0, stream>>>(A2c, Wb, V, nv2);
    gemm2_kernel<<<2048, 256, 0, stream>>>(A1c, V, nv1, nv2, bias, cand, cnt);
    final_kernel<<<BC, 1024, 0, stream>>>(cand, cnt, out);
}

// Round 9
// 248.374 us; speedup vs baseline: 1.4459x; 1.0552x over previous
//
#include <hip/hip_runtime.h>

typedef __bf16 bf16_t;
typedef bf16_t bf16x8 __attribute__((ext_vector_type(8)));
typedef float floatx4 __attribute__((ext_vector_type(4)));

#define L1C 512
#define L2C 512
#define BC  32
#define DC  1024
#define KTOP 256
#define NBIN 4096           // 12-bit bins: sign+exp+3 mantissa bits
#define CAP  512            // per-block candidate slots (64x64 tile)
#define NT   64             // tiles per batch in gemm2 (8x8)
#define FBUF 16384          // final-stage LDS candidate buffer

__device__ __forceinline__ unsigned short f2bf(float f) {
    unsigned u = __float_as_uint(f);
    u += 0x7FFFu + ((u >> 16) & 1u);   // RNE (data has no NaNs)
    return (unsigned short)(u >> 16);
}

// async global->LDS, 16B per lane; LDS dest = wave-uniform base + lane*16
__device__ __forceinline__ void g2l16(const unsigned short* g, unsigned short* l) {
    __builtin_amdgcn_global_load_lds((const unsigned int*)g, (unsigned int*)l,
                                     16, 0, 0);
}

__device__ __forceinline__ float decode_key(unsigned k) {
    return __uint_as_float(k & 0x7FFFFFFFu);
}

// ---- scan: per-batch valid-row index lists for both masks + cnt zero ----
__global__ __launch_bounds__(512) void scan_kernel(
    const int* __restrict__ mask1, const int* __restrict__ mask2,
    int* __restrict__ idx1, int* __restrict__ idx2,
    unsigned* __restrict__ nv1, unsigned* __restrict__ nv2,
    unsigned* __restrict__ cnt) {
    __shared__ unsigned sc[512];
    int b = blockIdx.x, t = threadIdx.x;
    for (int which = 0; which < 2; which++) {
        const int* m = which ? mask2 : mask1;
        int* idx = which ? idx2 : idx1;
        unsigned v = (m[t * BC + b] == 0) ? 1u : 0u;
        sc[t] = v;
        __syncthreads();
        for (int off = 1; off < 512; off <<= 1) {
            unsigned x = (t >= off) ? sc[t - off] : 0u;
            __syncthreads();
            sc[t] += x;
            __syncthreads();
        }
        if (v) idx[b * 512 + sc[t] - 1] = t;
        if (t == 511) { if (which) nv2[b] = sc[511]; else nv1[b] = sc[511]; }
        __syncthreads();
    }
    if (t < NT) cnt[b * NT + t] = 0;
}

// ---- prep: compacting casts of in1/in2 (+zero pad to x64), W cast ----
__global__ __launch_bounds__(256) void prep_kernel(
    const float* __restrict__ in1, const float* __restrict__ in2,
    const float* __restrict__ W,
    const int* __restrict__ idx1, const int* __restrict__ idx2,
    const unsigned* __restrict__ nv1, const unsigned* __restrict__ nv2,
    unsigned short* __restrict__ A1c, unsigned short* __restrict__ A2c,
    unsigned short* __restrict__ Wb) {
    int r = blockIdx.x, t = threadIdx.x;
    const float* src;
    unsigned short* dst;
    if (r < 2 * 16384) {
        int which = r >> 14;            // 0: in1, 1: in2
        int rr = r & 16383;
        int b = rr >> 9, vi = rr & 511;
        unsigned nv = which ? nv2[b] : nv1[b];
        unsigned pad = (nv + 63u) & ~63u;
        if ((unsigned)vi >= pad) return;
        dst = (which ? A2c : A1c) + ((size_t)b * 512 + vi) * DC;
        if ((unsigned)vi < nv) {
            int l = (which ? idx2 : idx1)[b * 512 + vi];
            src = (which ? in2 : in1) + (size_t)(l * BC + b) * DC;
        } else {
            ushort4 z = {0, 0, 0, 0};
            reinterpret_cast<ushort4*>(dst)[t] = z;
            return;
        }
    } else {
        int r3 = r - 2 * 16384;
        src = W + (size_t)r3 * DC;
        dst = Wb + (size_t)r3 * DC;
    }
    float4 v = reinterpret_cast<const float4*>(src)[t];
    ushort4 o;
    o.x = f2bf(v.x); o.y = f2bf(v.y); o.z = f2bf(v.z); o.w = f2bf(v.w);
    reinterpret_cast<ushort4*>(dst)[t] = o;
}

// ---- GEMM1: V[b][j][d] = sum_e A2c[b][j][e] * Wb[d][e] ----
// 128x128 tile, BK=64 via split-half LDS ([2][128][32]: conflict-free layout,
// lane-linear g2l16 dest). 32 MFMA per barrier pair, 16 K-iters.
__global__ __launch_bounds__(256) void gemm1_kernel(
    const unsigned short* __restrict__ A,    // A2c [32][512][1024]
    const unsigned short* __restrict__ Bt,   // Wb  [1024][1024]
    unsigned short* __restrict__ C,          // V   [32][512][1024]
    const unsigned* __restrict__ nv2) {
    int bi = blockIdx.x >> 2, mt = blockIdx.x & 3;
    unsigned pad2 = (nv2[bi] + 63u) & ~63u;
    if ((unsigned)(mt * 128) >= pad2) return;
    __shared__ unsigned short As[2][128][32];
    __shared__ unsigned short Bs[2][128][32];
    int tid = threadIdx.x;
    int wave = tid >> 6, lane = tid & 63;
    int lane15 = lane & 15, quad = lane >> 4;
    int wm = wave >> 1, wn = wave & 1;
    size_t m0 = (size_t)bi * 512 + mt * 128;
    size_t n0 = (size_t)blockIdx.y * 128;

    floatx4 zero = {0.f, 0.f, 0.f, 0.f};
    floatx4 acc[4][4];
#pragma unroll
    for (int i = 0; i < 4; i++)
#pragma unroll
        for (int j = 0; j < 4; j++) acc[i][j] = zero;

    for (int k0 = 0; k0 < DC; k0 += 64) {
#pragma unroll
        for (int c = 0; c < 4; c++) {
            int cid = c * 256 + tid;
            int h = cid >> 9, row = (cid >> 2) & 127, col8 = (cid & 3) * 8;
            unsigned short* lb = &As[0][0][0] + (c * 256 + wave * 64) * 8;
            g2l16(&A[(m0 + row) * DC + k0 + h * 32 + col8], lb);
            unsigned short* lb2 = &Bs[0][0][0] + (c * 256 + wave * 64) * 8;
            g2l16(&Bt[(n0 + row) * DC + k0 + h * 32 + col8], lb2);
        }
        __syncthreads();
#pragma unroll
        for (int h = 0; h < 2; h++) {
            bf16x8 af[4], bfr[4];
#pragma unroll
            for (int mi = 0; mi < 4; mi++)
                af[mi] = *reinterpret_cast<const bf16x8*>(
                    &As[h][wm * 64 + mi * 16 + lane15][quad * 8]);
#pragma unroll
            for (int ni = 0; ni < 4; ni++)
                bfr[ni] = *reinterpret_cast<const bf16x8*>(
                    &Bs[h][wn * 64 + ni * 16 + lane15][quad * 8]);
#pragma unroll
            for (int mi = 0; mi < 4; mi++)
#pragma unroll
                for (int ni = 0; ni < 4; ni++)
                    acc[mi][ni] = __builtin_amdgcn_mfma_f32_16x16x32_bf16(
                        af[mi], bfr[ni], acc[mi][ni], 0, 0, 0);
        }
        __syncthreads();
    }
#pragma unroll
    for (int mi = 0; mi < 4; mi++)
#pragma unroll
        for (int ni = 0; ni < 4; ni++)
#pragma unroll
            for (int r = 0; r < 4; r++) {
                size_t row = m0 + wm * 64 + mi * 16 + quad * 4 + r;
                size_t col = n0 + wn * 64 + ni * 16 + lane15;
                C[row * DC + col] = f2bf(acc[mi][ni][r]);
            }
}

// ---- GEMM2: 64x64 tiles, BK=64 split-half; relu + bias; top-k cands ----
__global__ __launch_bounds__(256) void gemm2_kernel(
    const unsigned short* __restrict__ A1c,  // [32][512][1024]
    const unsigned short* __restrict__ V,    // [32][512][1024]
    const unsigned* __restrict__ nv1, const unsigned* __restrict__ nv2,
    const float* __restrict__ bptr,
    unsigned* __restrict__ cand,             // [32*NT][CAP]
    unsigned* __restrict__ cnt) {            // [32*NT]
    // XCD swizzle: same xcd -> same batch
    int L = blockIdx.x;
    int xcd = L & 7, tile = (L >> 3) & 63, chunk = L >> 9;
    int b = xcd + (chunk << 3);
    int tx = tile & 7, ty = tile >> 3;
    int m0 = ty * 64, n0 = tx * 64;
    int gblk = b * NT + tile;
    int tid = threadIdx.x;
    unsigned nv1v = nv1[b], nv2v = nv2[b];
    unsigned pad1 = (nv1v + 63u) & ~63u, pad2 = (nv2v + 63u) & ~63u;
    if ((unsigned)m0 >= pad1 || (unsigned)n0 >= pad2) {
        if (tid == 0) cnt[gblk] = 0;
        return;
    }
    __shared__ unsigned short As[2][64][32];
    __shared__ unsigned short Bs[2][64][32];
    __shared__ unsigned lh[NBIN];
    __shared__ unsigned csum[256];
    __shared__ unsigned sel_c, sel_a, tsh, lcnt, zeq;
    int wave = tid >> 6, lane = tid & 63;
    int lane15 = lane & 15, quad = lane >> 4;
    const unsigned short* Ab = A1c + (size_t)b * 512 * DC;
    const unsigned short* Bb = V + (size_t)b * 512 * DC;

    for (int i = tid; i < NBIN; i += 256) lh[i] = 0;
    if (tid == 0) { sel_c = 0xFFFFFFFFu; lcnt = 0; zeq = 0; }

    floatx4 zero = {0.f, 0.f, 0.f, 0.f};
    floatx4 acc[4];
#pragma unroll
    for (int i = 0; i < 4; i++) acc[i] = zero;

    for (int k0 = 0; k0 < DC; k0 += 64) {
#pragma unroll
        for (int c = 0; c < 2; c++) {
            int cid = c * 256 + tid;   // [0,512)
            int h = cid >> 8, row = (cid >> 2) & 63, col8 = (cid & 3) * 8;
            unsigned short* lb = &As[0][0][0] + (c * 256 + wave * 64) * 8;
            g2l16(&Ab[(size_t)(m0 + row) * DC + k0 + h * 32 + col8], lb);
            unsigned short* lb2 = &Bs[0][0][0] + (c * 256 + wave * 64) * 8;
            g2l16(&Bb[(size_t)(n0 + row) * DC + k0 + h * 32 + col8], lb2);
        }
        __syncthreads();
#pragma unroll
        for (int h = 0; h < 2; h++) {
            bf16x8 af, bfr[4];
            af = *reinterpret_cast<const bf16x8*>(
                &As[h][wave * 16 + lane15][quad * 8]);
#pragma unroll
            for (int ni = 0; ni < 4; ni++)
                bfr[ni] = *reinterpret_cast<const bf16x8*>(
                    &Bs[h][ni * 16 + lane15][quad * 8]);
#pragma unroll
            for (int ni = 0; ni < 4; ni++)
                acc[ni] = __builtin_amdgcn_mfma_f32_16x16x32_bf16(
                    af, bfr[ni], acc[ni], 0, 0, 0);
        }
        __syncthreads();
    }

    float bias = bptr[0];
    // pass 1: 4096-bin histogram (zero scores privatized)
    unsigned zc = 0;
#pragma unroll
    for (int ni = 0; ni < 4; ni++) {
        int jl = n0 + ni * 16 + lane15;
        int v2 = (unsigned)jl < nv2v;
#pragma unroll
        for (int r = 0; r < 4; r++) {
            int il = m0 + wave * 16 + quad * 4 + r;
            float s = acc[ni][r] + bias;
            if (v2 && (unsigned)il < nv1v) {
                if (s > 0.f)
                    atomicAdd(&lh[(__float_as_uint(s) | 0x80000000u) >> 20], 1u);
                else
                    zc++;
            }
        }
    }
    if (zc) atomicAdd(&lh[2048], zc);
    __syncthreads();
    unsigned s16 = 0;
#pragma unroll
    for (int i = 0; i < 16; i++) s16 += lh[tid * 16 + i];
    csum[tid] = s16;
    __syncthreads();
    // parallel suffix scan over 256 chunks
    for (int off = 1; off < 256; off <<= 1) {
        unsigned v = (tid + off < 256) ? csum[tid + off] : 0u;
        __syncthreads();
        csum[tid] += v;
        __syncthreads();
    }
    {   // locate chunk holding the 256th (valid chunks are >=128)
        unsigned above = (tid < 255) ? csum[tid + 1] : 0u;
        if (tid >= 128 && csum[tid] >= KTOP && above < KTOP) {
            sel_c = (unsigned)tid; sel_a = above;
        }
    }
    __syncthreads();
    if (tid == 0) {
        if (sel_c == 0xFFFFFFFFu) {
            tsh = 2048u << 20;          // fewer than k valid: take all
        } else {
            unsigned cum = sel_a, bin = 2048;
            for (int bb = (int)sel_c * 16 + 15; bb >= (int)sel_c * 16; --bb) {
                unsigned hb = lh[bb];
                if (cum + hb >= KTOP) { bin = (unsigned)bb; break; }
                cum += hb;
            }
            tsh = bin << 20;
        }
    }
    __syncthreads();
    // pass 2: emit; exact-T ties gated to <= KTOP
    unsigned T = tsh;
    unsigned base = (unsigned)gblk * CAP;
#pragma unroll
    for (int ni = 0; ni < 4; ni++) {
        int jl = n0 + ni * 16 + lane15;
        int v2 = (unsigned)jl < nv2v;
#pragma unroll
        for (int r = 0; r < 4; r++) {
            int il = m0 + wave * 16 + quad * 4 + r;
            float s = acc[ni][r] + bias;
            s = s > 0.f ? s : 0.f;
            unsigned key = (v2 && (unsigned)il < nv1v)
                               ? (__float_as_uint(s) | 0x80000000u) : 0u;
            if (key > T) {
                unsigned p = atomicAdd(&lcnt, 1u);
                if (p < CAP) cand[base + p] = key;
            } else if (key == T) {
                unsigned z = atomicAdd(&zeq, 1u);
                if (z < KTOP) {
                    unsigned p = atomicAdd(&lcnt, 1u);
                    if (p < CAP) cand[base + p] = key;
                }
            }
        }
    }
    __syncthreads();
    if (tid == 0) cnt[gblk] = lcnt < CAP ? lcnt : CAP;
}

// ---- final: per batch, EXACT top-256 via 3-pass LDS radix select ----
__global__ __launch_bounds__(1024) void final_kernel(
    const unsigned* __restrict__ cand, const unsigned* __restrict__ cnt,
    float* __restrict__ out) {
    __shared__ unsigned buf[FBUF];     // 64 KB
    __shared__ unsigned h[NBIN];       // 16 KB
    __shared__ unsigned ss[256];
    __shared__ unsigned scnt_s[NT], off_s[NT];
    __shared__ unsigned ntot_s, sel_c, sel_a, B_s, R_s, mcount;
    __shared__ int have_s;
    __shared__ unsigned srt[256];
    int b = blockIdx.x, tid = threadIdx.x;
    int wv = tid >> 6, ln = tid & 63;

    if (tid < NT) {
        unsigned c = cnt[b * NT + tid];
        scnt_s[tid] = c < CAP ? c : CAP;
    }
    __syncthreads();
    if (tid == 0) {
        unsigned o = 0;
        for (int i = 0; i < NT; i++) {
            unsigned c = scnt_s[i];
            if (o + c > FBUF) c = (o < FBUF) ? FBUF - o : 0;
            scnt_s[i] = c;
            off_s[i] = o;
            o += c;
        }
        ntot_s = o;
        have_s = 1;
    }
    __syncthreads();
    // wave-parallel staging: wave wv handles segments wv, wv+16, ...
    for (int s = wv; s < NT; s += 16) {
        unsigned c = scnt_s[s], o = off_s[s];
        const unsigned* p = cand + (size_t)(b * NT + s) * CAP;
        for (unsigned i = ln; i < c; i += 64) buf[o + i] = p[i];
    }
    __syncthreads();
    unsigned n = ntot_s;

    unsigned Kr = KTOP;
    unsigned pfx = 0;
    unsigned kth = 0;
    for (int pass = 0; pass < 3; pass++) {
        int bins = (pass < 2) ? NBIN : 256;
        int shift = (pass == 0) ? 20 : (pass == 1) ? 8 : 0;
        int nch = bins >> 4;
        for (int i = tid; i < bins; i += 1024) h[i] = 0;
        __syncthreads();
        for (unsigned i = tid; i < n; i += 1024) {
            unsigned k = buf[i];
            bool ok = (pass == 0) ||
                      (pass == 1 && (k >> 20) == pfx) ||
                      (pass == 2 && (k >> 8) == pfx);
            if (ok) atomicAdd(&h[(k >> shift) & (bins - 1)], 1u);
        }
        __syncthreads();
        if (tid < nch) {
            unsigned s = 0;
#pragma unroll
            for (int i = 0; i < 16; i++) s += h[tid * 16 + i];
            ss[tid] = s;
        }
        __syncthreads();
        for (int off = 1; off < nch; off <<= 1) {
            unsigned v = 0;
            if (tid < nch && tid + (unsigned)off < (unsigned)nch) v = ss[tid + off];
            __syncthreads();
            if (tid < nch) ss[tid] += v;
            __syncthreads();
        }
        if (pass == 0) {
            if (tid == 0) have_s = (ss[0] >= KTOP);
            __syncthreads();
            if (!have_s) break;
        }
        if (tid < nch) {
            unsigned above = (tid + 1 < (unsigned)nch) ? ss[tid + 1] : 0u;
            if (above < Kr && ss[tid] >= Kr) { sel_c = tid; sel_a = above; }
        }
        __syncthreads();
        if (tid == 0) {
            unsigned cum = sel_a;
            for (int bb = (int)sel_c * 16 + 15; bb >= (int)sel_c * 16; --bb) {
                unsigned hb = h[bb];
                if (cum + hb >= Kr) { B_s = (unsigned)bb; R_s = Kr - cum; break; }
                cum += hb;
            }
        }
        __syncthreads();
        unsigned Bv = B_s;
        Kr = R_s;
        if (pass == 0) pfx = Bv;
        else if (pass == 1) pfx = (pfx << 12) | Bv;
        else kth = (pfx << 8) | Bv;
        __syncthreads();
    }

    if (tid == 0) mcount = 0;
    __syncthreads();
    int have = have_s;
    unsigned lim = have ? kth : 0u;
    for (unsigned i = tid; i < n; i += 1024) {
        unsigned k = buf[i];
        if (k > lim) {
            unsigned p = atomicAdd(&mcount, 1u);
            if (p < 256) srt[p] = k;
        }
    }
    __syncthreads();
    unsigned m = mcount;
    if (tid < 256 && tid >= (int)m) srt[tid] = have ? kth : 0u;
    for (int k2 = 2; k2 <= 256; k2 <<= 1) {
        for (int j2 = k2 >> 1; j2 > 0; j2 >>= 1) {
            __syncthreads();
            if (tid < 256) {
                int ixj = tid ^ j2;
                if (ixj > tid) {
                    unsigned a = srt[tid], c = srt[ixj];
                    bool up = (tid & k2) == 0;
                    if (up ? (a < c) : (a > c)) { srt[tid] = c; srt[ixj] = a; }
                }
            }
        }
    }
    __syncthreads();
    if (tid < 256) {
        unsigned nval = have ? KTOP : (m < KTOP ? m : KTOP);
        float v;
        if ((unsigned)tid < nval) v = decode_key(srt[tid]);
        else v = (nval > 0) ? decode_key(srt[nval - 1]) : -__builtin_inff();
        out[b * KTOP + tid] = v;
    }
}

// ---------------- launch ----------------
extern "C" void kernel_launch(void* const* d_in, const int* in_sizes, int n_in,
                              void* d_out, int out_size, void* d_ws, size_t ws_size,
                              hipStream_t stream) {
    const float* in1   = (const float*)d_in[0];   // [512,32,1024]
    const float* in2   = (const float*)d_in[1];   // [512,32,1024]
    const int*   mask1 = (const int*)d_in[2];     // [512,32]
    const int*   mask2 = (const int*)d_in[3];     // [512,32]
    const float* W     = (const float*)d_in[4];   // [1024,1024]
    const float* bias  = (const float*)d_in[5];   // [1]
    float* out = (float*)d_out;

    char* ws = (char*)d_ws;
    size_t off = 0;
    const size_t nElem = (size_t)512 * BC * DC;
    unsigned short* A1c = (unsigned short*)(ws + off); off += nElem * 2;      // 32 MB
    unsigned short* A2c = (unsigned short*)(ws + off); off += nElem * 2;      // 32 MB
    unsigned short* Wb  = (unsigned short*)(ws + off); off += (size_t)DC * DC * 2; // 2 MB
    unsigned short* V   = (unsigned short*)(ws + off); off += nElem * 2;      // 32 MB
    unsigned* cand = (unsigned*)(ws + off); off += (size_t)BC * NT * CAP * 4; // 4 MB
    unsigned* cnt  = (unsigned*)(ws + off); off += (size_t)BC * NT * 4;
    int* idx1 = (int*)(ws + off); off += (size_t)BC * 512 * 4;
    int* idx2 = (int*)(ws + off); off += (size_t)BC * 512 * 4;
    unsigned* nv1 = (unsigned*)(ws + off); off += BC * 4;
    unsigned* nv2 = (unsigned*)(ws + off); off += BC * 4;

    scan_kernel<<<BC, 512, 0, stream>>>(mask1, mask2, idx1, idx2, nv1, nv2, cnt);
    prep_kernel<<<2 * 16384 + 1024, 256, 0, stream>>>(
        in1, in2, W, idx1, idx2, nv1, nv2, A1c, A2c, Wb);
    gemm1_kernel<<<dim3(128, 8), 256, 0, stream>>>(A2c, Wb, V, nv2);
    gemm2_kernel<<<2048, 256, 0, stream>>>(A1c, V, nv1, nv2, bias, cand, cnt);
    final_kernel<<<BC, 1024, 0, stream>>>(cand, cnt, out);
}